// Round 5
// baseline (941.587 us; speedup 1.0000x reference)
//
#include <hip/hip_runtime.h>

typedef short short8 __attribute__((ext_vector_type(8)));
typedef float f32x4 __attribute__((ext_vector_type(4)));

__device__ __forceinline__ unsigned short f2bu(float f) {
  unsigned u = __builtin_bit_cast(unsigned, f);
  u += 0x7fffu + ((u >> 16) & 1u);
  return (unsigned short)(u >> 16);
}

__device__ __forceinline__ float b2f(unsigned short b) {
  unsigned u = (unsigned)b << 16;
  return __builtin_bit_cast(float, u);
}

__device__ __forceinline__ float gelu_t(float x) {
  float x3 = x * x * x;
  float t = tanhf(0.7978845608028654f * (x + 0.044715f * x3));
  return 0.5f * x * (1.f + t);
}

__device__ __forceinline__ void gload16(const void* g, void* l) {
  __builtin_amdgcn_global_load_lds(
      (const __attribute__((address_space(1))) void*)g,
      (__attribute__((address_space(3))) void*)l, 16, 0, 0);
}

// ---------------- small prep ----------------
__global__ __launch_bounds__(256) void prep_small(
    const float* __restrict__ vec, const float* __restrict__ sol_t,
    float* __restrict__ silu_vec, float* __restrict__ scales) {
  __shared__ float red[4];
  int t = threadIdx.x;
  float v = (t < 64) ? sol_t[t] : 0.f;
#pragma unroll
  for (int o = 32; o > 0; o >>= 1) v += __shfl_down(v, o);
  if ((t & 63) == 0) red[t >> 6] = v;
  __syncthreads();
  if (t == 0) {
    float m = (red[0] + red[1] + red[2] + red[3]) * (1.f / 64.f);
    m = fmaxf(m, 0.1f);
    const float sc = 0.08838834764831845f;  // 128^-0.5
    scales[0] = sc;
    scales[1] = sc / m;  // s_eff^2 folded into score scale
  }
  for (int k = t; k < 2048; k += 256) {
    float x = vec[k];
    silu_vec[k] = x / (1.f + expf(-x));
  }
}

__global__ __launch_bounds__(256) void mod_kernel(
    const float* __restrict__ S, const float* __restrict__ mw,
    const float* __restrict__ mb, float* __restrict__ modb) {
  int idx = blockIdx.x * 256 + threadIdx.x;  // 16*2048
  int h = idx >> 11, n = idx & 2047;
  int y = n >> 5, x = n & 31;
  float cy = (y + 0.5f) * 0.125f - 0.5f;
  float cx = (x + 0.5f) * 0.25f - 0.5f;
  int y0 = (int)floorf(cy); float fy = cy - (float)y0;
  int x0 = (int)floorf(cx); float fx = cx - (float)x0;
  int y0c = min(max(y0, 0), 7), y1c = min(max(y0 + 1, 0), 7);
  int x0c = min(max(x0, 0), 7), x1c = min(max(x0 + 1, 0), 7);
  float v = (1.f - fy) * ((1.f - fx) * S[y0c * 8 + x0c] + fx * S[y0c * 8 + x1c]) +
            fy * ((1.f - fx) * S[y1c * 8 + x0c] + fx * S[y1c * 8 + x1c]);
  float t = v * mw[h] + mb[h];
  t = fminf(fmaxf(t, -2.f), 2.f);
  modb[idx] = expf(t);
}

__global__ __launch_bounds__(256) void ada_gemv(
    const float* __restrict__ sv,
    const float* __restrict__ Wi, const float* __restrict__ bi,
    const float* __restrict__ Wt, const float* __restrict__ bt,
    float* __restrict__ ei, float* __restrict__ et) {
  __shared__ float red[4][64];
  const float* W = blockIdx.y ? Wt : Wi;
  const float* bb = blockIdx.y ? bt : bi;
  float* e = blockIdx.y ? et : ei;
  int jl = threadIdx.x & 63, ks = threadIdx.x >> 6;
  int j = blockIdx.x * 64 + jl;
  float acc = 0.f;
  int k0 = ks * 512;
#pragma unroll 4
  for (int k = 0; k < 512; ++k) acc += sv[k0 + k] * W[(size_t)(k0 + k) * 12288 + j];
  red[ks][jl] = acc;
  __syncthreads();
  if (ks == 0) e[j] = red[0][jl] + red[1][jl] + red[2][jl] + red[3][jl] + bb[j];
}

// ---------------- RMSNorm + adaLN modulate -> bf16 ----------------
__global__ __launch_bounds__(256) void rmsmod_kernel(
    const float* __restrict__ X, const float* __restrict__ nw,
    const float* __restrict__ e, int sh_off, int sc_off,
    unsigned short* __restrict__ out) {
  __shared__ float red[4];
  int r = blockIdx.x, t = threadIdx.x;
  const float4* xr = reinterpret_cast<const float4*>(X + (size_t)r * 2048);
  float4 v0 = xr[t * 2], v1 = xr[t * 2 + 1];
  float ss = v0.x * v0.x + v0.y * v0.y + v0.z * v0.z + v0.w * v0.w +
             v1.x * v1.x + v1.y * v1.y + v1.z * v1.z + v1.w * v1.w;
#pragma unroll
  for (int o = 32; o > 0; o >>= 1) ss += __shfl_down(ss, o);
  if ((t & 63) == 0) red[t >> 6] = ss;
  __syncthreads();
  float rinv = rsqrtf((red[0] + red[1] + red[2] + red[3]) * (1.f / 2048.f) + 1e-6f);
  int c0 = t * 8;
  float xv[8] = {v0.x, v0.y, v0.z, v0.w, v1.x, v1.y, v1.z, v1.w};
  short8 ov;
#pragma unroll
  for (int i = 0; i < 8; ++i) {
    int c = c0 + i;
    float y = xv[i] * rinv * nw[c] * (1.f + e[sc_off + c]) + e[sh_off + c];
    ov[i] = (short)f2bu(y);
  }
  *reinterpret_cast<short8*>(out + (size_t)r * 2048 + c0) = ov;
}

// ---------------- weight transpose+convert ----------------
__global__ __launch_bounds__(256) void transpose_w(
    const float* __restrict__ W, unsigned short* __restrict__ Bt, int K, int N) {
  __shared__ float tile[32][33];
  int n0 = blockIdx.x * 32, k0 = blockIdx.y * 32;
  int tx = threadIdx.x, ty = threadIdx.y;
#pragma unroll
  for (int j = 0; j < 32; j += 8)
    tile[ty + j][tx] = W[(size_t)(k0 + ty + j) * N + n0 + tx];
  __syncthreads();
#pragma unroll
  for (int j = 0; j < 32; j += 8)
    Bt[(size_t)(n0 + ty + j) * K + k0 + tx] = f2bu(tile[tx][ty + j]);
}

__global__ __launch_bounds__(256) void transpose_v(
    const unsigned short* __restrict__ V, unsigned short* __restrict__ Vt) {
  __shared__ unsigned short tile[32][33];
  int h = blockIdx.z;
  int s0 = blockIdx.x * 32, d0 = blockIdx.y * 32;
  int tx = threadIdx.x, ty = threadIdx.y;
  const unsigned short* src = V + (size_t)h * 2560 * 128;
  unsigned short* dst = Vt + (size_t)h * 128 * 2560;
#pragma unroll
  for (int j = 0; j < 32; j += 8)
    tile[ty + j][tx] = src[(size_t)(s0 + ty + j) * 128 + d0 + tx];
  __syncthreads();
#pragma unroll
  for (int j = 0; j < 32; j += 8)
    dst[(size_t)(d0 + ty + j) * 2560 + s0 + tx] = tile[tx][ty + j];
}

// ---------------- batched GEMM (txt rows 0..511, img rows 512..2559) ----------------
struct GemmP {
  const unsigned short *A, *Bt_t, *Bt_i;
  float* C;
  unsigned short* Cb;
  const float *bias_t, *bias_i;
  const float *rope, *modb;
  unsigned short *q_txt, *q_img, *k_cat, *v_cat;
  const float* scales;
  int Mb_t;
  int N, K, KS;
};

template <int EPI>
__global__ __launch_bounds__(256) void gemm2(GemmP p) {
  __shared__ int4 sA[128 * 8];
  __shared__ int4 sB[128 * 8];
  const int NB = gridDim.x, MBT = gridDim.y;
  int nwg = NB * MBT;
  int orig = blockIdx.y * NB + blockIdx.x;
  int qq = nwg >> 3, rr = nwg & 7, xcd = orig & 7, base = orig >> 3;
  int sw = (xcd < rr ? xcd * (qq + 1) : rr * (qq + 1) + (xcd - rr) * qq) + base;
  int bx = sw / MBT, by = sw % MBT;
  const bool is_t = by < p.Mb_t;
  const unsigned short* Bt = is_t ? p.Bt_t : p.Bt_i;
  const int m0 = by * 128, n0 = bx * 128;
  const int z = blockIdx.z;
  const int Kz = p.K / p.KS, kbeg = z * Kz, kend = kbeg + Kz;
  const int tid = threadIdx.x;
  const int w = tid >> 6, l = tid & 63, lr = l & 15, lg = l >> 4;
  const int wm = (w >> 1) * 64, wn = (w & 1) * 64;
  f32x4 acc[4][4] = {};
  const int4* Ag = reinterpret_cast<const int4*>(p.A);
  const int4* Bg = reinterpret_cast<const int4*>(Bt);
  const int K8 = p.K >> 3;
  const short8* pA = reinterpret_cast<const short8*>(sA);
  const short8* pB = reinterpret_cast<const short8*>(sB);
  int srow[4], sch[4];
#pragma unroll
  for (int i = 0; i < 4; ++i) {
    int s = i * 256 + tid;
    srow[i] = s >> 3;
    sch[i] = (s & 7) ^ (srow[i] & 7);
  }
  for (int k0 = kbeg; k0 < kend; k0 += 64) {
    __syncthreads();
    int kc = k0 >> 3;
#pragma unroll
    for (int i = 0; i < 4; ++i) {
      gload16(&Ag[(size_t)(m0 + srow[i]) * K8 + kc + sch[i]], &sA[i * 256 + w * 64]);
      gload16(&Bg[(size_t)(n0 + srow[i]) * K8 + kc + sch[i]], &sB[i * 256 + w * 64]);
    }
    __syncthreads();
#pragma unroll
    for (int kk = 0; kk < 2; ++kk) {
      short8 af[4], bf[4];
#pragma unroll
      for (int m = 0; m < 4; ++m) {
        int row = wm + m * 16 + lr;
        af[m] = pA[row * 8 + ((kk * 4 + lg) ^ (row & 7))];
      }
#pragma unroll
      for (int n = 0; n < 4; ++n) {
        int row = wn + n * 16 + lr;
        bf[n] = pB[row * 8 + ((kk * 4 + lg) ^ (row & 7))];
      }
#pragma unroll
      for (int m = 0; m < 4; ++m)
#pragma unroll
        for (int n = 0; n < 4; ++n)
          acc[m][n] = __builtin_amdgcn_mfma_f32_16x16x32_bf16(af[m], bf[n], acc[m][n], 0, 0, 0);
    }
  }
  if (EPI == 0) {
    float* C = p.C + (size_t)z * MBT * 128 * p.N;
#pragma unroll
    for (int m = 0; m < 4; ++m)
#pragma unroll
      for (int n = 0; n < 4; ++n)
#pragma unroll
        for (int j = 0; j < 4; ++j) {
          int r = m0 + wm + m * 16 + lg * 4 + j;
          int cc = n0 + wn + n * 16 + lr;
          C[(size_t)r * p.N + cc] = acc[m][n][j];
        }
  } else if (EPI == 1) {
    const float* bias = is_t ? p.bias_t : p.bias_i;
#pragma unroll
    for (int n = 0; n < 4; ++n) {
      int cc = n0 + wn + n * 16 + lr;
      float bv = bias[cc];
#pragma unroll
      for (int m = 0; m < 4; ++m)
#pragma unroll
        for (int j = 0; j < 4; ++j) {
          int r = m0 + wm + m * 16 + lg * 4 + j;
          p.Cb[(size_t)r * p.N + cc] = f2bu(gelu_t(acc[m][n][j] + bv));
        }
    }
  } else {
    // qkv epilogue: q pre-scaled by softmax scale (txt: scales[0], img: scales[1])
    int sel = bx >> 4, h = bx & 15;
#pragma unroll
    for (int n = 0; n < 4; ++n) {
      int d = wn + n * 16 + lr;
#pragma unroll
      for (int m = 0; m < 4; ++m)
#pragma unroll
        for (int j = 0; j < 4; ++j) {
          int r = m0 + wm + m * 16 + lg * 4 + j;
          float v = acc[m][n][j];
          if (is_t) {
            if (sel == 0) p.q_txt[((size_t)h * 512 + r) * 128 + d] = f2bu(v * p.scales[0]);
            else if (sel == 1) p.k_cat[((size_t)h * 2560 + r) * 128 + d] = f2bu(v);
            else p.v_cat[((size_t)h * 2560 + r) * 128 + d] = f2bu(v);
          } else {
            int s = r - 512;
            if (sel == 2) {
              p.v_cat[((size_t)h * 2560 + r) * 128 + d] = f2bu(v);
            } else {
              float c = p.rope[s * 128 + (d & ~1)];
              float sn = p.rope[s * 128 + (d | 1)];
              float part = __shfl_xor(v, 1);
              float vr = (d & 1) ? v * c + part * sn : v * c - part * sn;
              vr *= p.modb[h * 2048 + s];
              if (sel == 0) p.q_img[((size_t)h * 2048 + s) * 128 + d] = f2bu(vr * p.scales[1]);
              else p.k_cat[((size_t)h * 2560 + r) * 128 + d] = f2bu(vr);
            }
          }
        }
    }
  }
}

// ---------------- split-KV flash attention, 2-phase pipelined ----------------
// grid (20, 16, 4). K/V double-buffered; prefetch of tile t+1 issued before
// computing tile t; raw s_barrier + counted vmcnt keeps loads in flight.
// P overlays the consumed K buffer (after post-QK barrier). LDS = 64 KB.
__global__ __launch_bounds__(256) void attn_kernel(
    const unsigned short* __restrict__ q_txt, const unsigned short* __restrict__ q_img,
    const unsigned short* __restrict__ Kc, const unsigned short* __restrict__ Vt,
    unsigned short* __restrict__ Op, float* __restrict__ ml) {
  __shared__ int4 kb[2][64 * 16];   // [64 kv][128 d] bf16, x2 = 32KB (P overlays kb[cur])
  __shared__ int4 vb[2][128 * 8];   // [128 d][64 kv] bf16, x2 = 32KB
  const int tid = threadIdx.x, w = tid >> 6, l = tid & 63, lr = l & 15, lg = l >> 4;
  const int bx = blockIdx.x, h = blockIdx.y, z = blockIdx.z;
  const bool is_t = bx < 4;
  const int orow = is_t ? bx * 128 : 512 + (bx - 4) * 128;
  const unsigned short* Qp = is_t ? q_txt + ((size_t)h * 512 + bx * 128) * 128
                                  : q_img + ((size_t)h * 2048 + (bx - 4) * 128) * 128;
  short8 aq[2][4];
#pragma unroll
  for (int m = 0; m < 2; ++m)
#pragma unroll
    for (int ds = 0; ds < 4; ++ds) {
      int row = w * 32 + m * 16 + lr;
      aq[m][ds] = *reinterpret_cast<const short8*>(Qp + (size_t)row * 128 + ds * 32 + lg * 8);
    }
  const int4* Kg = reinterpret_cast<const int4*>(Kc + (size_t)h * 2560 * 128);
  const int4* Vg = reinterpret_cast<const int4*>(Vt + (size_t)h * 128 * 2560);
  int krow[4], kch[4], vrow[4], vch[4];
#pragma unroll
  for (int i = 0; i < 4; ++i) {
    int s = i * 256 + tid;
    krow[i] = s >> 4; kch[i] = (s & 15) ^ (krow[i] & 7);
    vrow[i] = s >> 3; vch[i] = (s & 7) ^ (vrow[i] & 7);
  }
  const int kbeg = z * 10, kend = kbeg + 10;
  // prologue: stage tile kbeg
  {
    int4* dK = kb[kbeg & 1];
    int4* dV = vb[kbeg & 1];
#pragma unroll
    for (int i = 0; i < 4; ++i) {
      gload16(&Kg[(size_t)(kbeg * 64 + krow[i]) * 16 + kch[i]], &dK[i * 256 + w * 64]);
      gload16(&Vg[(size_t)vrow[i] * 320 + kbeg * 8 + vch[i]], &dV[i * 256 + w * 64]);
    }
  }
  f32x4 oacc[2][8] = {};
  float m_run[2][4], l_run[2][4];
#pragma unroll
  for (int m = 0; m < 2; ++m)
#pragma unroll
    for (int j = 0; j < 4; ++j) { m_run[m][j] = -1e30f; l_run[m][j] = 0.f; }

  for (int kt = kbeg; kt < kend; ++kt) {
    const int cur = kt & 1;
    if (kt + 1 < kend) {
      int4* dK = kb[cur ^ 1];
      int4* dV = vb[cur ^ 1];
#pragma unroll
      for (int i = 0; i < 4; ++i) {
        gload16(&Kg[(size_t)((kt + 1) * 64 + krow[i]) * 16 + kch[i]], &dK[i * 256 + w * 64]);
        gload16(&Vg[(size_t)vrow[i] * 320 + (kt + 1) * 8 + vch[i]], &dV[i * 256 + w * 64]);
      }
      asm volatile("s_waitcnt vmcnt(8)" ::: "memory");
    } else {
      asm volatile("s_waitcnt vmcnt(0)" ::: "memory");
    }
    __builtin_amdgcn_sched_barrier(0);
    __builtin_amdgcn_s_barrier();  // tile kt K/V visible to all waves
    const short8* pK = reinterpret_cast<const short8*>(kb[cur]);
    const short8* pV = reinterpret_cast<const short8*>(vb[cur]);
    f32x4 sacc[2][4] = {};
    __builtin_amdgcn_s_setprio(1);
#pragma unroll
    for (int ds = 0; ds < 4; ++ds) {
      short8 bk[4];
#pragma unroll
      for (int n = 0; n < 4; ++n) {
        int row = n * 16 + lr;
        bk[n] = pK[row * 16 + ((ds * 4 + lg) ^ (row & 7))];
      }
#pragma unroll
      for (int m = 0; m < 2; ++m)
#pragma unroll
        for (int n = 0; n < 4; ++n)
          sacc[m][n] = __builtin_amdgcn_mfma_f32_16x16x32_bf16(aq[m][ds], bk[n], sacc[m][n], 0, 0, 0);
    }
    __builtin_amdgcn_s_setprio(0);
    float corr_[2][4];
#pragma unroll
    for (int m = 0; m < 2; ++m)
#pragma unroll
      for (int j = 0; j < 4; ++j) {
        float mx = -1e30f;
#pragma unroll
        for (int n = 0; n < 4; ++n) mx = fmaxf(mx, sacc[m][n][j]);
        mx = fmaxf(mx, __shfl_xor(mx, 1));
        mx = fmaxf(mx, __shfl_xor(mx, 2));
        mx = fmaxf(mx, __shfl_xor(mx, 4));
        mx = fmaxf(mx, __shfl_xor(mx, 8));
        float mn = fmaxf(m_run[m][j], mx);
        float corr = __expf(m_run[m][j] - mn);
        m_run[m][j] = mn;
        float rs = 0.f;
#pragma unroll
        for (int n = 0; n < 4; ++n) {
          float pp = __expf(sacc[m][n][j] - mn);
          sacc[m][n][j] = pp;
          rs += pp;
        }
        rs += __shfl_xor(rs, 1);
        rs += __shfl_xor(rs, 2);
        rs += __shfl_xor(rs, 4);
        rs += __shfl_xor(rs, 8);
        l_run[m][j] = l_run[m][j] * corr + rs;
        corr_[m][j] = corr;
      }
#pragma unroll
    for (int m = 0; m < 2; ++m)
#pragma unroll
      for (int n = 0; n < 8; ++n)
#pragma unroll
        for (int j = 0; j < 4; ++j) oacc[m][n][j] *= corr_[m][j];
    __builtin_amdgcn_s_barrier();  // all waves done reading kb[cur] -> safe to overwrite with P
    unsigned short* sPb = reinterpret_cast<unsigned short*>(kb[cur]);
#pragma unroll
    for (int m = 0; m < 2; ++m)
#pragma unroll
      for (int n = 0; n < 4; ++n)
#pragma unroll
        for (int j = 0; j < 4; ++j) {
          int row = w * 32 + m * 16 + lg * 4 + j;
          int col = n * 16 + lr;
          sPb[row * 64 + (((col >> 3) ^ (row & 7)) << 3) + (col & 7)] = f2bu(sacc[m][n][j]);
        }
    const short8* pP = reinterpret_cast<const short8*>(kb[cur]);
    __builtin_amdgcn_s_setprio(1);
#pragma unroll
    for (int kk = 0; kk < 2; ++kk) {
      short8 ap[2], bv[8];
#pragma unroll
      for (int m = 0; m < 2; ++m) {
        int row = w * 32 + m * 16 + lr;
        ap[m] = pP[row * 8 + ((kk * 4 + lg) ^ (row & 7))];
      }
#pragma unroll
      for (int n = 0; n < 8; ++n) {
        int row = n * 16 + lr;
        bv[n] = pV[row * 8 + ((kk * 4 + lg) ^ (row & 7))];
      }
#pragma unroll
      for (int m = 0; m < 2; ++m)
#pragma unroll
        for (int n = 0; n < 8; ++n)
          oacc[m][n] = __builtin_amdgcn_mfma_f32_16x16x32_bf16(ap[m], bv[n], oacc[m][n], 0, 0, 0);
    }
    __builtin_amdgcn_s_setprio(0);
    __builtin_amdgcn_s_barrier();  // protect kb[cur] (P) / vb[cur] before next prefetch overwrite
  }
  const size_t zbase = (size_t)z * 40960 + (size_t)h * 2560 + orow;
#pragma unroll
  for (int m = 0; m < 2; ++m)
#pragma unroll
    for (int j = 0; j < 4; ++j) {
      int row = w * 32 + m * 16 + lg * 4 + j;
#pragma unroll
      for (int n = 0; n < 8; ++n)
        Op[(zbase + row) * 128 + n * 16 + lr] = f2bu(oacc[m][n][j]);
      if (lr == 0) {
        ml[(zbase + row) * 2] = m_run[m][j];
        ml[(zbase + row) * 2 + 1] = l_run[m][j];
      }
    }
}

// merge 4 KV-chunk partials (LSE combine) -> ao[r][h*128+d] bf16
__global__ __launch_bounds__(256) void attn_merge(
    const unsigned short* __restrict__ Op, const float* __restrict__ ml,
    unsigned short* __restrict__ ao) {
  int gid = blockIdx.x * 256 + threadIdx.x;  // 40960 rows * 32 threads
  int rid = gid >> 5, d0 = (gid & 31) * 4;
  int h = rid / 2560;
  int r = rid - h * 2560;
  float M = -1e30f;
#pragma unroll
  for (int z = 0; z < 4; ++z) M = fmaxf(M, ml[((size_t)z * 40960 + rid) * 2]);
  float L = 0.f, o0 = 0.f, o1 = 0.f, o2 = 0.f, o3 = 0.f;
#pragma unroll
  for (int z = 0; z < 4; ++z) {
    size_t sidx = (size_t)z * 40960 + rid;
    float mz = ml[sidx * 2], lz = ml[sidx * 2 + 1];
    float wgt = __expf(mz - M);
    L += wgt * lz;
    ushort4 v = *reinterpret_cast<const ushort4*>(Op + sidx * 128 + d0);
    o0 += wgt * b2f(v.x); o1 += wgt * b2f(v.y);
    o2 += wgt * b2f(v.z); o3 += wgt * b2f(v.w);
  }
  float inv = 1.f / L;
  ushort4 ov;
  ov.x = f2bu(o0 * inv); ov.y = f2bu(o1 * inv);
  ov.z = f2bu(o2 * inv); ov.w = f2bu(o3 * inv);
  *reinterpret_cast<ushort4*>(ao + (size_t)r * 2048 + h * 128 + d0) = ov;
}

// ---------------- residuals (sum 2 split-K partials) ----------------
__global__ __launch_bounds__(256) void residual1(
    const float4* __restrict__ X, const float4* __restrict__ P0,
    const float4* __restrict__ P1, const float* __restrict__ e,
    float4* __restrict__ out, int total4) {
  int stride = gridDim.x * 256;
  for (int i = blockIdx.x * 256 + threadIdx.x; i < total4; i += stride) {
    int c = (i * 4) & 2047;
    float4 g = *reinterpret_cast<const float4*>(e + 4096 + c);
    float4 x = X[i], p0 = P0[i], p1 = P1[i], o;
    o.x = x.x + g.x * (p0.x + p1.x); o.y = x.y + g.y * (p0.y + p1.y);
    o.z = x.z + g.z * (p0.z + p1.z); o.w = x.w + g.w * (p0.w + p1.w);
    out[i] = o;
  }
}

__global__ __launch_bounds__(256) void residual2(
    const float4* __restrict__ P0, const float4* __restrict__ P1,
    const float* __restrict__ b2, const float* __restrict__ e,
    float4* __restrict__ out, int total4) {
  int stride = gridDim.x * 256;
  for (int i = blockIdx.x * 256 + threadIdx.x; i < total4; i += stride) {
    int c = (i * 4) & 2047;
    float4 g = *reinterpret_cast<const float4*>(e + 10240 + c);
    float4 bb = *reinterpret_cast<const float4*>(b2 + c);
    float4 p0 = P0[i], p1 = P1[i], o = out[i];
    o.x += g.x * (p0.x + p1.x + bb.x); o.y += g.y * (p0.y + p1.y + bb.y);
    o.z += g.z * (p0.z + p1.z + bb.z); o.w += g.w * (p0.w + p1.w + bb.w);
    out[i] = o;
  }
}

extern "C" void kernel_launch(void* const* d_in, const int* in_sizes, int n_in,
                              void* d_out, int out_size, void* d_ws, size_t ws_size,
                              hipStream_t stream) {
  (void)in_sizes; (void)n_in; (void)out_size; (void)ws_size;
  const float* txt = (const float*)d_in[0];
  const float* img = (const float*)d_in[1];
  const float* vec = (const float*)d_in[2];
  const float* rope = (const float*)d_in[3];
  const float* sol_t = (const float*)d_in[4];
  const float* sol_s = (const float*)d_in[5];
  const float* ada_img_w = (const float*)d_in[6];
  const float* ada_img_b = (const float*)d_in[7];
  const float* ada_img_nw = (const float*)d_in[8];
  const float* ada_txt_w = (const float*)d_in[9];
  const float* ada_txt_b = (const float*)d_in[10];
  const float* ada_txt_nw = (const float*)d_in[11];
  const float* txt_qkv_w = (const float*)d_in[12];
  const float* img_qkv_w = (const float*)d_in[13];
  const float* txt_out_w = (const float*)d_in[14];
  const float* img_out_w = (const float*)d_in[15];
  const float* mod_w = (const float*)d_in[16];
  const float* mod_b = (const float*)d_in[17];
  const float* img_n2_w = (const float*)d_in[18];
  const float* txt_n2_w = (const float*)d_in[19];
  const float* img_fc1_w = (const float*)d_in[20];
  const float* img_fc1_b = (const float*)d_in[21];
  const float* img_fc2_w = (const float*)d_in[22];
  const float* img_fc2_b = (const float*)d_in[23];
  const float* txt_fc1_w = (const float*)d_in[24];
  const float* txt_fc1_b = (const float*)d_in[25];
  const float* txt_fc2_w = (const float*)d_in[26];
  const float* txt_fc2_b = (const float*)d_in[27];
  float* out = (float*)d_out;
  float* out_img = out + (size_t)512 * 2048;
  char* ws = (char*)d_ws;

  const size_t MB = 1 << 20;
  float* silu_vec = (float*)(ws + 0);
  float* scales = (float*)(ws + 8192);
  float* modb = (float*)(ws + 16384);
  float* e_img = (float*)(ws + 147456);
  float* e_txt = (float*)(ws + 196608);
  unsigned short* wt0 = (unsigned short*)(ws + 1 * MB);    // 32MB txt weights
  unsigned short* wt1 = (unsigned short*)(ws + 33 * MB);   // 32MB img weights
  unsigned short* Opart = (unsigned short*)(ws + 1 * MB);  // 40MB (overlays weights, dead then)
  float* mlbuf = (float*)(ws + 42 * MB);                   // 1.25MB
  unsigned short* actA = (unsigned short*)(ws + 65 * MB);  // [2560][2048] bf16, 10MB
  char* attn_base = ws + 75 * MB;                          // 50MB region
  unsigned short* q_txt = (unsigned short*)(attn_base);
  unsigned short* q_img = (unsigned short*)(attn_base + 2 * MB);
  unsigned short* k_cat = (unsigned short*)(attn_base + 10 * MB);
  unsigned short* v_cat = (unsigned short*)(attn_base + 20 * MB);
  unsigned short* vT = (unsigned short*)(attn_base + 30 * MB);
  unsigned short* ao = (unsigned short*)(attn_base + 40 * MB);
  unsigned short* actB = (unsigned short*)attn_base;  // [2560][8192] bf16 (MLP phase)
  float* Cbuf = (float*)(ws + 125 * MB);  // 2 partials x [2560][2048] f32 = 40MB
  const size_t PSTR = (size_t)2560 * 2048;

  prep_small<<<1, 256, 0, stream>>>(vec, sol_t, silu_vec, scales);
  mod_kernel<<<128, 256, 0, stream>>>(sol_s, mod_w, mod_b, modb);
  ada_gemv<<<dim3(192, 2), 256, 0, stream>>>(silu_vec, ada_img_w, ada_img_b,
                                             ada_txt_w, ada_txt_b, e_img, e_txt);
  rmsmod_kernel<<<512, 256, 0, stream>>>(txt, ada_txt_nw, e_txt, 0, 2048, actA);
  rmsmod_kernel<<<2048, 256, 0, stream>>>(img, ada_img_nw, e_img, 0, 2048,
                                          actA + (size_t)512 * 2048);
  transpose_w<<<dim3(192, 64), dim3(32, 8), 0, stream>>>(txt_qkv_w, wt0, 2048, 6144);
  transpose_w<<<dim3(192, 64), dim3(32, 8), 0, stream>>>(img_qkv_w, wt1, 2048, 6144);
  {
    GemmP p = {actA, wt0, wt1, nullptr, nullptr, nullptr, nullptr,
               rope, modb, q_txt, q_img, k_cat, v_cat, scales, 4, 6144, 2048, 1};
    gemm2<2><<<dim3(48, 20, 1), 256, 0, stream>>>(p);
  }
  transpose_v<<<dim3(80, 4, 16), dim3(32, 8), 0, stream>>>(v_cat, vT);
  attn_kernel<<<dim3(20, 16, 4), 256, 0, stream>>>(q_txt, q_img, k_cat, vT, Opart, mlbuf);
  attn_merge<<<5120, 256, 0, stream>>>(Opart, mlbuf, ao);
  transpose_w<<<dim3(64, 64), dim3(32, 8), 0, stream>>>(txt_out_w, wt0, 2048, 2048);
  transpose_w<<<dim3(64, 64), dim3(32, 8), 0, stream>>>(img_out_w, wt1, 2048, 2048);
  {
    GemmP p = {ao, wt0, wt1, Cbuf, nullptr, nullptr, nullptr,
               nullptr, nullptr, nullptr, nullptr, nullptr, nullptr, nullptr, 4, 2048, 2048, 2};
    gemm2<0><<<dim3(16, 20, 2), 256, 0, stream>>>(p);
  }
  residual1<<<512, 256, 0, stream>>>((const float4*)txt, (const float4*)Cbuf,
                                     (const float4*)(Cbuf + PSTR), e_txt,
                                     (float4*)out, 512 * 2048 / 4);
  residual1<<<1024, 256, 0, stream>>>((const float4*)img,
                                      (const float4*)(Cbuf + (size_t)512 * 2048),
                                      (const float4*)(Cbuf + PSTR + (size_t)512 * 2048), e_img,
                                      (float4*)out_img, 2048 * 2048 / 4);
  rmsmod_kernel<<<512, 256, 0, stream>>>(out, txt_n2_w, e_txt, 6144, 8192, actA);
  rmsmod_kernel<<<2048, 256, 0, stream>>>(out_img, img_n2_w, e_img, 6144, 8192,
                                          actA + (size_t)512 * 2048);
  transpose_w<<<dim3(256, 64), dim3(32, 8), 0, stream>>>(txt_fc1_w, wt0, 2048, 8192);
  transpose_w<<<dim3(256, 64), dim3(32, 8), 0, stream>>>(img_fc1_w, wt1, 2048, 8192);
  {
    GemmP p = {actA, wt0, wt1, nullptr, actB, txt_fc1_b, img_fc1_b,
               nullptr, nullptr, nullptr, nullptr, nullptr, nullptr, nullptr, 4, 8192, 2048, 1};
    gemm2<1><<<dim3(64, 20, 1), 256, 0, stream>>>(p);
  }
  transpose_w<<<dim3(64, 256), dim3(32, 8), 0, stream>>>(txt_fc2_w, wt0, 8192, 2048);
  transpose_w<<<dim3(64, 256), dim3(32, 8), 0, stream>>>(img_fc2_w, wt1, 8192, 2048);
  {
    GemmP p = {actB, wt0, wt1, Cbuf, nullptr, nullptr, nullptr,
               nullptr, nullptr, nullptr, nullptr, nullptr, nullptr, nullptr, 4, 2048, 8192, 2};
    gemm2<0><<<dim3(16, 20, 2), 256, 0, stream>>>(p);
  }
  residual2<<<512, 256, 0, stream>>>((const float4*)Cbuf, (const float4*)(Cbuf + PSTR),
                                     txt_fc2_b, e_txt, (float4*)out, 512 * 2048 / 4);
  residual2<<<1024, 256, 0, stream>>>((const float4*)(Cbuf + (size_t)512 * 2048),
                                      (const float4*)(Cbuf + PSTR + (size_t)512 * 2048),
                                      img_fc2_b, e_img, (float4*)out_img, 2048 * 2048 / 4);
}

// Round 6
// 939.678 us; speedup vs baseline: 1.0020x; 1.0020x over previous
//
#include <hip/hip_runtime.h>

typedef short short8 __attribute__((ext_vector_type(8)));
typedef float f32x4 __attribute__((ext_vector_type(4)));

__device__ __forceinline__ unsigned short f2bu(float f) {
  unsigned u = __builtin_bit_cast(unsigned, f);
  u += 0x7fffu + ((u >> 16) & 1u);
  return (unsigned short)(u >> 16);
}

__device__ __forceinline__ float b2f(unsigned short b) {
  unsigned u = (unsigned)b << 16;
  return __builtin_bit_cast(float, u);
}

__device__ __forceinline__ float gelu_t(float x) {
  float x3 = x * x * x;
  float t = tanhf(0.7978845608028654f * (x + 0.044715f * x3));
  return 0.5f * x * (1.f + t);
}

__device__ __forceinline__ void gload16(const void* g, void* l) {
  __builtin_amdgcn_global_load_lds(
      (const __attribute__((address_space(1))) void*)g,
      (__attribute__((address_space(3))) void*)l, 16, 0, 0);
}

// ---------------- small prep ----------------
__global__ __launch_bounds__(256) void prep_small(
    const float* __restrict__ vec, const float* __restrict__ sol_t,
    float* __restrict__ silu_vec, float* __restrict__ scales) {
  __shared__ float red[4];
  int t = threadIdx.x;
  float v = (t < 64) ? sol_t[t] : 0.f;
#pragma unroll
  for (int o = 32; o > 0; o >>= 1) v += __shfl_down(v, o);
  if ((t & 63) == 0) red[t >> 6] = v;
  __syncthreads();
  if (t == 0) {
    float m = (red[0] + red[1] + red[2] + red[3]) * (1.f / 64.f);
    m = fmaxf(m, 0.1f);
    const float sc = 0.08838834764831845f;   // 128^-0.5
    const float l2e = 1.4426950408889634f;   // scores computed in log2 domain
    scales[0] = sc * l2e;
    scales[1] = sc / m * l2e;  // s_eff^2 folded into score scale
  }
  for (int k = t; k < 2048; k += 256) {
    float x = vec[k];
    silu_vec[k] = x / (1.f + expf(-x));
  }
}

__global__ __launch_bounds__(256) void mod_kernel(
    const float* __restrict__ S, const float* __restrict__ mw,
    const float* __restrict__ mb, float* __restrict__ modb) {
  int idx = blockIdx.x * 256 + threadIdx.x;  // 16*2048
  int h = idx >> 11, n = idx & 2047;
  int y = n >> 5, x = n & 31;
  float cy = (y + 0.5f) * 0.125f - 0.5f;
  float cx = (x + 0.5f) * 0.25f - 0.5f;
  int y0 = (int)floorf(cy); float fy = cy - (float)y0;
  int x0 = (int)floorf(cx); float fx = cx - (float)x0;
  int y0c = min(max(y0, 0), 7), y1c = min(max(y0 + 1, 0), 7);
  int x0c = min(max(x0, 0), 7), x1c = min(max(x0 + 1, 0), 7);
  float v = (1.f - fy) * ((1.f - fx) * S[y0c * 8 + x0c] + fx * S[y0c * 8 + x1c]) +
            fy * ((1.f - fx) * S[y1c * 8 + x0c] + fx * S[y1c * 8 + x1c]);
  float t = v * mw[h] + mb[h];
  t = fminf(fmaxf(t, -2.f), 2.f);
  modb[idx] = expf(t);
}

__global__ __launch_bounds__(256) void ada_gemv(
    const float* __restrict__ sv,
    const float* __restrict__ Wi, const float* __restrict__ bi,
    const float* __restrict__ Wt, const float* __restrict__ bt,
    float* __restrict__ ei, float* __restrict__ et) {
  __shared__ float red[4][64];
  const float* W = blockIdx.y ? Wt : Wi;
  const float* bb = blockIdx.y ? bt : bi;
  float* e = blockIdx.y ? et : ei;
  int jl = threadIdx.x & 63, ks = threadIdx.x >> 6;
  int j = blockIdx.x * 64 + jl;
  float acc = 0.f;
  int k0 = ks * 512;
#pragma unroll 4
  for (int k = 0; k < 512; ++k) acc += sv[k0 + k] * W[(size_t)(k0 + k) * 12288 + j];
  red[ks][jl] = acc;
  __syncthreads();
  if (ks == 0) e[j] = red[0][jl] + red[1][jl] + red[2][jl] + red[3][jl] + bb[j];
}

// ---------------- RMSNorm + adaLN modulate -> bf16 ----------------
__global__ __launch_bounds__(256) void rmsmod_kernel(
    const float* __restrict__ X, const float* __restrict__ nw,
    const float* __restrict__ e, int sh_off, int sc_off,
    unsigned short* __restrict__ out) {
  __shared__ float red[4];
  int r = blockIdx.x, t = threadIdx.x;
  const float4* xr = reinterpret_cast<const float4*>(X + (size_t)r * 2048);
  float4 v0 = xr[t * 2], v1 = xr[t * 2 + 1];
  float ss = v0.x * v0.x + v0.y * v0.y + v0.z * v0.z + v0.w * v0.w +
             v1.x * v1.x + v1.y * v1.y + v1.z * v1.z + v1.w * v1.w;
#pragma unroll
  for (int o = 32; o > 0; o >>= 1) ss += __shfl_down(ss, o);
  if ((t & 63) == 0) red[t >> 6] = ss;
  __syncthreads();
  float rinv = rsqrtf((red[0] + red[1] + red[2] + red[3]) * (1.f / 2048.f) + 1e-6f);
  int c0 = t * 8;
  float xv[8] = {v0.x, v0.y, v0.z, v0.w, v1.x, v1.y, v1.z, v1.w};
  short8 ov;
#pragma unroll
  for (int i = 0; i < 8; ++i) {
    int c = c0 + i;
    float y = xv[i] * rinv * nw[c] * (1.f + e[sc_off + c]) + e[sh_off + c];
    ov[i] = (short)f2bu(y);
  }
  *reinterpret_cast<short8*>(out + (size_t)r * 2048 + c0) = ov;
}

// ---------------- weight transpose+convert: f32 [K][N] -> bf16 [N][K] ----------------
// 64k x 32n tiles, packed u32 writes (full-width stores).
__global__ __launch_bounds__(256) void transpose_w(
    const float* __restrict__ W, unsigned short* __restrict__ Bt, int K, int N) {
  __shared__ float tile[64][33];
  int n0 = blockIdx.x * 32, k0 = blockIdx.y * 64;
  int tx = threadIdx.x, ty = threadIdx.y;
#pragma unroll
  for (int j = 0; j < 8; ++j)
    tile[ty + j * 8][tx] = W[(size_t)(k0 + ty + j * 8) * N + n0 + tx];
  __syncthreads();
#pragma unroll
  for (int j = 0; j < 4; ++j) {
    int n = ty + j * 8;
    float lo = tile[2 * tx][n], hi = tile[2 * tx + 1][n];
    unsigned pk = (unsigned)f2bu(lo) | ((unsigned)f2bu(hi) << 16);
    *reinterpret_cast<unsigned*>(Bt + (size_t)(n0 + n) * K + k0 + 2 * tx) = pk;
  }
}

__global__ __launch_bounds__(256) void transpose_v(
    const unsigned short* __restrict__ V, unsigned short* __restrict__ Vt) {
  __shared__ unsigned short tile[32][33];
  int h = blockIdx.z;
  int s0 = blockIdx.x * 32, d0 = blockIdx.y * 32;
  int tx = threadIdx.x, ty = threadIdx.y;
  const unsigned short* src = V + (size_t)h * 2560 * 128;
  unsigned short* dst = Vt + (size_t)h * 128 * 2560;
#pragma unroll
  for (int j = 0; j < 32; j += 8)
    tile[ty + j][tx] = src[(size_t)(s0 + ty + j) * 128 + d0 + tx];
  __syncthreads();
#pragma unroll
  for (int j = 0; j < 32; j += 8)
    dst[(size_t)(d0 + ty + j) * 2560 + s0 + tx] = tile[tx][ty + j];
}

// ---------------- batched GEMM (txt rows 0..511, img rows 512..2559) ----------------
struct GemmP {
  const unsigned short *A, *Bt_t, *Bt_i;
  float* C;
  unsigned short* Cb;
  const float *bias_t, *bias_i;
  const float *rope, *modb;
  unsigned short *q_txt, *q_img, *k_cat, *v_cat;
  const float* scales;
  int Mb_t;
  int N, K, KS;
};

template <int EPI>
__global__ __launch_bounds__(256) void gemm2(GemmP p) {
  __shared__ int4 sA[128 * 8];
  __shared__ int4 sB[128 * 8];
  const int NB = gridDim.x, MBT = gridDim.y;
  int nwg = NB * MBT;
  int orig = blockIdx.y * NB + blockIdx.x;
  int qq = nwg >> 3, rr = nwg & 7, xcd = orig & 7, base = orig >> 3;
  int sw = (xcd < rr ? xcd * (qq + 1) : rr * (qq + 1) + (xcd - rr) * qq) + base;
  int bx = sw / MBT, by = sw % MBT;
  const bool is_t = by < p.Mb_t;
  const unsigned short* Bt = is_t ? p.Bt_t : p.Bt_i;
  const int m0 = by * 128, n0 = bx * 128;
  const int z = blockIdx.z;
  const int Kz = p.K / p.KS, kbeg = z * Kz, kend = kbeg + Kz;
  const int tid = threadIdx.x;
  const int w = tid >> 6, l = tid & 63, lr = l & 15, lg = l >> 4;
  const int wm = (w >> 1) * 64, wn = (w & 1) * 64;
  f32x4 acc[4][4] = {};
  const int4* Ag = reinterpret_cast<const int4*>(p.A);
  const int4* Bg = reinterpret_cast<const int4*>(Bt);
  const int K8 = p.K >> 3;
  const short8* pA = reinterpret_cast<const short8*>(sA);
  const short8* pB = reinterpret_cast<const short8*>(sB);
  int srow[4], sch[4];
#pragma unroll
  for (int i = 0; i < 4; ++i) {
    int s = i * 256 + tid;
    srow[i] = s >> 3;
    sch[i] = (s & 7) ^ (srow[i] & 7);
  }
  for (int k0 = kbeg; k0 < kend; k0 += 64) {
    __syncthreads();
    int kc = k0 >> 3;
#pragma unroll
    for (int i = 0; i < 4; ++i) {
      gload16(&Ag[(size_t)(m0 + srow[i]) * K8 + kc + sch[i]], &sA[i * 256 + w * 64]);
      gload16(&Bg[(size_t)(n0 + srow[i]) * K8 + kc + sch[i]], &sB[i * 256 + w * 64]);
    }
    __syncthreads();
#pragma unroll
    for (int kk = 0; kk < 2; ++kk) {
      short8 af[4], bf[4];
#pragma unroll
      for (int m = 0; m < 4; ++m) {
        int row = wm + m * 16 + lr;
        af[m] = pA[row * 8 + ((kk * 4 + lg) ^ (row & 7))];
      }
#pragma unroll
      for (int n = 0; n < 4; ++n) {
        int row = wn + n * 16 + lr;
        bf[n] = pB[row * 8 + ((kk * 4 + lg) ^ (row & 7))];
      }
#pragma unroll
      for (int m = 0; m < 4; ++m)
#pragma unroll
        for (int n = 0; n < 4; ++n)
          acc[m][n] = __builtin_amdgcn_mfma_f32_16x16x32_bf16(af[m], bf[n], acc[m][n], 0, 0, 0);
    }
  }
  if (EPI == 0) {
    float* C = p.C + (size_t)z * MBT * 128 * p.N;
#pragma unroll
    for (int m = 0; m < 4; ++m)
#pragma unroll
      for (int n = 0; n < 4; ++n)
#pragma unroll
        for (int j = 0; j < 4; ++j) {
          int r = m0 + wm + m * 16 + lg * 4 + j;
          int cc = n0 + wn + n * 16 + lr;
          C[(size_t)r * p.N + cc] = acc[m][n][j];
        }
  } else if (EPI == 1) {
    const float* bias = is_t ? p.bias_t : p.bias_i;
#pragma unroll
    for (int n = 0; n < 4; ++n) {
      int cc = n0 + wn + n * 16 + lr;
      float bv = bias[cc];
#pragma unroll
      for (int m = 0; m < 4; ++m)
#pragma unroll
        for (int j = 0; j < 4; ++j) {
          int r = m0 + wm + m * 16 + lg * 4 + j;
          p.Cb[(size_t)r * p.N + cc] = f2bu(gelu_t(acc[m][n][j] + bv));
        }
    }
  } else {
    // qkv epilogue: q pre-scaled (incl. log2e) by scales[0]/scales[1]
    int sel = bx >> 4, h = bx & 15;
#pragma unroll
    for (int n = 0; n < 4; ++n) {
      int d = wn + n * 16 + lr;
#pragma unroll
      for (int m = 0; m < 4; ++m)
#pragma unroll
        for (int j = 0; j < 4; ++j) {
          int r = m0 + wm + m * 16 + lg * 4 + j;
          float v = acc[m][n][j];
          if (is_t) {
            if (sel == 0) p.q_txt[((size_t)h * 512 + r) * 128 + d] = f2bu(v * p.scales[0]);
            else if (sel == 1) p.k_cat[((size_t)h * 2560 + r) * 128 + d] = f2bu(v);
            else p.v_cat[((size_t)h * 2560 + r) * 128 + d] = f2bu(v);
          } else {
            int s = r - 512;
            if (sel == 2) {
              p.v_cat[((size_t)h * 2560 + r) * 128 + d] = f2bu(v);
            } else {
              float c = p.rope[s * 128 + (d & ~1)];
              float sn = p.rope[s * 128 + (d | 1)];
              float part = __shfl_xor(v, 1);
              float vr = (d & 1) ? v * c + part * sn : v * c - part * sn;
              vr *= p.modb[h * 2048 + s];
              if (sel == 0) p.q_img[((size_t)h * 2048 + s) * 128 + d] = f2bu(vr * p.scales[1]);
              else p.k_cat[((size_t)h * 2560 + r) * 128 + d] = f2bu(vr);
            }
          }
        }
    }
  }
}

// ---------------- split-KV flash attention, 2-barrier pipelined ----------------
// Scores in log2 domain (Q pre-scaled by scale*log2e). Dedicated P buffer
// (wave-private rows -> no P barrier). Defer-max (THR=11 log2). LDS = 80KB.
__global__ __launch_bounds__(256) void attn_kernel(
    const unsigned short* __restrict__ q_txt, const unsigned short* __restrict__ q_img,
    const unsigned short* __restrict__ Kc, const unsigned short* __restrict__ Vt,
    unsigned short* __restrict__ Op, float* __restrict__ ml) {
  __shared__ int4 kb[2][64 * 16];   // [64 kv][128 d] bf16, x2 = 32KB
  __shared__ int4 vb[2][128 * 8];   // [128 d][64 kv] bf16, x2 = 32KB
  __shared__ int4 pb[128 * 8];      // [128 q][64 kv] bf16 = 16KB
  const int tid = threadIdx.x, w = tid >> 6, l = tid & 63, lr = l & 15, lg = l >> 4;
  const int bx = blockIdx.x, h = blockIdx.y, z = blockIdx.z;
  const bool is_t = bx < 4;
  const int orow = is_t ? bx * 128 : 512 + (bx - 4) * 128;
  const unsigned short* Qp = is_t ? q_txt + ((size_t)h * 512 + bx * 128) * 128
                                  : q_img + ((size_t)h * 2048 + (bx - 4) * 128) * 128;
  short8 aq[2][4];
#pragma unroll
  for (int m = 0; m < 2; ++m)
#pragma unroll
    for (int ds = 0; ds < 4; ++ds) {
      int row = w * 32 + m * 16 + lr;
      aq[m][ds] = *reinterpret_cast<const short8*>(Qp + (size_t)row * 128 + ds * 32 + lg * 8);
    }
  const int4* Kg = reinterpret_cast<const int4*>(Kc + (size_t)h * 2560 * 128);
  const int4* Vg = reinterpret_cast<const int4*>(Vt + (size_t)h * 128 * 2560);
  int krow[4], kch[4], vrow[4], vch[4];
#pragma unroll
  for (int i = 0; i < 4; ++i) {
    int s = i * 256 + tid;
    krow[i] = s >> 4; kch[i] = (s & 15) ^ (krow[i] & 7);
    vrow[i] = s >> 3; vch[i] = (s & 7) ^ (vrow[i] & 7);
  }
  const int kbeg = z * 10, kend = kbeg + 10;
  {
    int4* dK = kb[kbeg & 1];
    int4* dV = vb[kbeg & 1];
#pragma unroll
    for (int i = 0; i < 4; ++i) {
      gload16(&Kg[(size_t)(kbeg * 64 + krow[i]) * 16 + kch[i]], &dK[i * 256 + w * 64]);
      gload16(&Vg[(size_t)vrow[i] * 320 + kbeg * 8 + vch[i]], &dV[i * 256 + w * 64]);
    }
  }
  f32x4 oacc[2][8] = {};
  float m_run[2][4], l_run[2][4];
#pragma unroll
  for (int m = 0; m < 2; ++m)
#pragma unroll
    for (int j = 0; j < 4; ++j) { m_run[m][j] = -1e30f; l_run[m][j] = 0.f; }
  const short8* pP = reinterpret_cast<const short8*>(pb);
  unsigned short* sPb = reinterpret_cast<unsigned short*>(pb);

  for (int kt = kbeg; kt < kend; ++kt) {
    const int cur = kt & 1;
    if (kt + 1 < kend) {
      int4* dK = kb[cur ^ 1];
      int4* dV = vb[cur ^ 1];
#pragma unroll
      for (int i = 0; i < 4; ++i) {
        gload16(&Kg[(size_t)((kt + 1) * 64 + krow[i]) * 16 + kch[i]], &dK[i * 256 + w * 64]);
        gload16(&Vg[(size_t)vrow[i] * 320 + (kt + 1) * 8 + vch[i]], &dV[i * 256 + w * 64]);
      }
      asm volatile("s_waitcnt vmcnt(8)" ::: "memory");
    } else {
      asm volatile("s_waitcnt vmcnt(0)" ::: "memory");
    }
    __builtin_amdgcn_sched_barrier(0);
    __builtin_amdgcn_s_barrier();  // SB1: kb[cur]/vb[cur] ready on all waves
    const short8* pK = reinterpret_cast<const short8*>(kb[cur]);
    const short8* pV = reinterpret_cast<const short8*>(vb[cur]);
    f32x4 sacc[2][4] = {};
    __builtin_amdgcn_s_setprio(1);
#pragma unroll
    for (int ds = 0; ds < 4; ++ds) {
      short8 bk[4];
#pragma unroll
      for (int n = 0; n < 4; ++n) {
        int row = n * 16 + lr;
        bk[n] = pK[row * 16 + ((ds * 4 + lg) ^ (row & 7))];
      }
#pragma unroll
      for (int m = 0; m < 2; ++m)
#pragma unroll
        for (int n = 0; n < 4; ++n)
          sacc[m][n] = __builtin_amdgcn_mfma_f32_16x16x32_bf16(aq[m][ds], bk[n], sacc[m][n], 0, 0, 0);
    }
    __builtin_amdgcn_s_setprio(0);
    // softmax in log2 domain with defer-max; P written fused with exp loop
    float corr_[2][4];
    bool grow_any = false;
#pragma unroll
    for (int m = 0; m < 2; ++m)
#pragma unroll
      for (int j = 0; j < 4; ++j) {
        float mx = fmaxf(fmaxf(sacc[m][0][j], sacc[m][1][j]),
                         fmaxf(sacc[m][2][j], sacc[m][3][j]));
        mx = fmaxf(mx, __shfl_xor(mx, 1));
        mx = fmaxf(mx, __shfl_xor(mx, 2));
        mx = fmaxf(mx, __shfl_xor(mx, 4));
        mx = fmaxf(mx, __shfl_xor(mx, 8));
        bool grow = mx > m_run[m][j] + 11.0f;
        grow_any |= grow;
        float mn = grow ? mx : m_run[m][j];
        corr_[m][j] = exp2f(m_run[m][j] - mn);  // == 1.0 when deferred
        m_run[m][j] = mn;
        float rs = 0.f;
        int prow = w * 32 + m * 16 + lg * 4 + j;
#pragma unroll
        for (int n = 0; n < 4; ++n) {
          float pp = exp2f(sacc[m][n][j] - mn);
          rs += pp;
          int col = n * 16 + lr;
          sPb[prow * 64 + (((col >> 3) ^ (prow & 7)) << 3) + (col & 7)] = f2bu(pp);
        }
        rs += __shfl_xor(rs, 1);
        rs += __shfl_xor(rs, 2);
        rs += __shfl_xor(rs, 4);
        rs += __shfl_xor(rs, 8);
        l_run[m][j] = fmaf(l_run[m][j], corr_[m][j], rs);
      }
    if (__any(grow_any)) {
#pragma unroll
      for (int m = 0; m < 2; ++m)
#pragma unroll
        for (int n = 0; n < 8; ++n)
#pragma unroll
          for (int j = 0; j < 4; ++j) oacc[m][n][j] *= corr_[m][j];
    }
    // PV: P rows are wave-private (write+read same wave) -> no barrier needed
    __builtin_amdgcn_s_setprio(1);
#pragma unroll
    for (int kk = 0; kk < 2; ++kk) {
      short8 ap[2], bv[8];
#pragma unroll
      for (int m = 0; m < 2; ++m) {
        int row = w * 32 + m * 16 + lr;
        ap[m] = pP[row * 8 + ((kk * 4 + lg) ^ (row & 7))];
      }
#pragma unroll
      for (int n = 0; n < 8; ++n) {
        int row = n * 16 + lr;
        bv[n] = pV[row * 8 + ((kk * 4 + lg) ^ (row & 7))];
      }
#pragma unroll
      for (int m = 0; m < 2; ++m)
#pragma unroll
        for (int n = 0; n < 8; ++n)
          oacc[m][n] = __builtin_amdgcn_mfma_f32_16x16x32_bf16(ap[m], bv[n], oacc[m][n], 0, 0, 0);
    }
    __builtin_amdgcn_s_setprio(0);
    __builtin_amdgcn_s_barrier();  // SB2: all waves done with kb/vb[cur] before next prefetch
  }
  const size_t zbase = (size_t)z * 40960 + (size_t)h * 2560 + orow;
#pragma unroll
  for (int m = 0; m < 2; ++m)
#pragma unroll
    for (int j = 0; j < 4; ++j) {
      int row = w * 32 + m * 16 + lg * 4 + j;
#pragma unroll
      for (int n = 0; n < 8; ++n)
        Op[(zbase + row) * 128 + n * 16 + lr] = f2bu(oacc[m][n][j]);
      if (lr == 0) {
        ml[(zbase + row) * 2] = m_run[m][j];
        ml[(zbase + row) * 2 + 1] = l_run[m][j];
      }
    }
}

// merge 4 KV-chunk partials (log2-domain LSE combine) -> ao[r][h*128+d] bf16
__global__ __launch_bounds__(256) void attn_merge(
    const unsigned short* __restrict__ Op, const float* __restrict__ ml,
    unsigned short* __restrict__ ao) {
  int gid = blockIdx.x * 256 + threadIdx.x;  // 40960 rows * 32 threads
  int rid = gid >> 5, d0 = (gid & 31) * 4;
  int h = rid / 2560;
  int r = rid - h * 2560;
  float M = -1e30f;
#pragma unroll
  for (int z = 0; z < 4; ++z) M = fmaxf(M, ml[((size_t)z * 40960 + rid) * 2]);
  float L = 0.f, o0 = 0.f, o1 = 0.f, o2 = 0.f, o3 = 0.f;
#pragma unroll
  for (int z = 0; z < 4; ++z) {
    size_t sidx = (size_t)z * 40960 + rid;
    float mz = ml[sidx * 2], lz = ml[sidx * 2 + 1];
    float wgt = exp2f(mz - M);
    L += wgt * lz;
    ushort4 v = *reinterpret_cast<const ushort4*>(Op + sidx * 128 + d0);
    o0 += wgt * b2f(v.x); o1 += wgt * b2f(v.y);
    o2 += wgt * b2f(v.z); o3 += wgt * b2f(v.w);
  }
  float inv = 1.f / L;
  ushort4 ov;
  ov.x = f2bu(o0 * inv); ov.y = f2bu(o1 * inv);
  ov.z = f2bu(o2 * inv); ov.w = f2bu(o3 * inv);
  *reinterpret_cast<ushort4*>(ao + (size_t)r * 2048 + h * 128 + d0) = ov;
}

// ---------------- residuals (sum 2 split-K partials) ----------------
__global__ __launch_bounds__(256) void residual1(
    const float4* __restrict__ X, const float4* __restrict__ P0,
    const float4* __restrict__ P1, const float* __restrict__ e,
    float4* __restrict__ out, int total4) {
  int stride = gridDim.x * 256;
  for (int i = blockIdx.x * 256 + threadIdx.x; i < total4; i += stride) {
    int c = (i * 4) & 2047;
    float4 g = *reinterpret_cast<const float4*>(e + 4096 + c);
    float4 x = X[i], p0 = P0[i], p1 = P1[i], o;
    o.x = x.x + g.x * (p0.x + p1.x); o.y = x.y + g.y * (p0.y + p1.y);
    o.z = x.z + g.z * (p0.z + p1.z); o.w = x.w + g.w * (p0.w + p1.w);
    out[i] = o;
  }
}

__global__ __launch_bounds__(256) void residual2(
    const float4* __restrict__ P0, const float4* __restrict__ P1,
    const float* __restrict__ b2, const float* __restrict__ e,
    float4* __restrict__ out, int total4) {
  int stride = gridDim.x * 256;
  for (int i = blockIdx.x * 256 + threadIdx.x; i < total4; i += stride) {
    int c = (i * 4) & 2047;
    float4 g = *reinterpret_cast<const float4*>(e + 10240 + c);
    float4 bb = *reinterpret_cast<const float4*>(b2 + c);
    float4 p0 = P0[i], p1 = P1[i], o = out[i];
    o.x += g.x * (p0.x + p1.x + bb.x); o.y += g.y * (p0.y + p1.y + bb.y);
    o.z += g.z * (p0.z + p1.z + bb.z); o.w += g.w * (p0.w + p1.w + bb.w);
    out[i] = o;
  }
}

extern "C" void kernel_launch(void* const* d_in, const int* in_sizes, int n_in,
                              void* d_out, int out_size, void* d_ws, size_t ws_size,
                              hipStream_t stream) {
  (void)in_sizes; (void)n_in; (void)out_size; (void)ws_size;
  const float* txt = (const float*)d_in[0];
  const float* img = (const float*)d_in[1];
  const float* vec = (const float*)d_in[2];
  const float* rope = (const float*)d_in[3];
  const float* sol_t = (const float*)d_in[4];
  const float* sol_s = (const float*)d_in[5];
  const float* ada_img_w = (const float*)d_in[6];
  const float* ada_img_b = (const float*)d_in[7];
  const float* ada_img_nw = (const float*)d_in[8];
  const float* ada_txt_w = (const float*)d_in[9];
  const float* ada_txt_b = (const float*)d_in[10];
  const float* ada_txt_nw = (const float*)d_in[11];
  const float* txt_qkv_w = (const float*)d_in[12];
  const float* img_qkv_w = (const float*)d_in[13];
  const float* txt_out_w = (const float*)d_in[14];
  const float* img_out_w = (const float*)d_in[15];
  const float* mod_w = (const float*)d_in[16];
  const float* mod_b = (const float*)d_in[17];
  const float* img_n2_w = (const float*)d_in[18];
  const float* txt_n2_w = (const float*)d_in[19];
  const float* img_fc1_w = (const float*)d_in[20];
  const float* img_fc1_b = (const float*)d_in[21];
  const float* img_fc2_w = (const float*)d_in[22];
  const float* img_fc2_b = (const float*)d_in[23];
  const float* txt_fc1_w = (const float*)d_in[24];
  const float* txt_fc1_b = (const float*)d_in[25];
  const float* txt_fc2_w = (const float*)d_in[26];
  const float* txt_fc2_b = (const float*)d_in[27];
  float* out = (float*)d_out;
  float* out_img = out + (size_t)512 * 2048;
  char* ws = (char*)d_ws;

  const size_t MB = 1 << 20;
  float* silu_vec = (float*)(ws + 0);
  float* scales = (float*)(ws + 8192);
  float* modb = (float*)(ws + 16384);
  float* e_img = (float*)(ws + 147456);
  float* e_txt = (float*)(ws + 196608);
  unsigned short* wt0 = (unsigned short*)(ws + 1 * MB);    // 32MB txt weights
  unsigned short* wt1 = (unsigned short*)(ws + 33 * MB);   // 32MB img weights
  unsigned short* Opart = (unsigned short*)(ws + 1 * MB);  // 40MB (overlays weights, dead then)
  float* mlbuf = (float*)(ws + 42 * MB);                   // 1.25MB
  unsigned short* actA = (unsigned short*)(ws + 65 * MB);  // [2560][2048] bf16, 10MB
  char* attn_base = ws + 75 * MB;                          // 50MB region
  unsigned short* q_txt = (unsigned short*)(attn_base);
  unsigned short* q_img = (unsigned short*)(attn_base + 2 * MB);
  unsigned short* k_cat = (unsigned short*)(attn_base + 10 * MB);
  unsigned short* v_cat = (unsigned short*)(attn_base + 20 * MB);
  unsigned short* vT = (unsigned short*)(attn_base + 30 * MB);
  unsigned short* ao = (unsigned short*)(attn_base + 40 * MB);
  unsigned short* actB = (unsigned short*)attn_base;  // [2560][8192] bf16 (MLP phase)
  float* Cbuf = (float*)(ws + 125 * MB);  // 2 partials x [2560][2048] f32 = 40MB
  const size_t PSTR = (size_t)2560 * 2048;

  prep_small<<<1, 256, 0, stream>>>(vec, sol_t, silu_vec, scales);
  mod_kernel<<<128, 256, 0, stream>>>(sol_s, mod_w, mod_b, modb);
  ada_gemv<<<dim3(192, 2), 256, 0, stream>>>(silu_vec, ada_img_w, ada_img_b,
                                             ada_txt_w, ada_txt_b, e_img, e_txt);
  rmsmod_kernel<<<512, 256, 0, stream>>>(txt, ada_txt_nw, e_txt, 0, 2048, actA);
  rmsmod_kernel<<<2048, 256, 0, stream>>>(img, ada_img_nw, e_img, 0, 2048,
                                          actA + (size_t)512 * 2048);
  transpose_w<<<dim3(192, 32), dim3(32, 8), 0, stream>>>(txt_qkv_w, wt0, 2048, 6144);
  transpose_w<<<dim3(192, 32), dim3(32, 8), 0, stream>>>(img_qkv_w, wt1, 2048, 6144);
  {
    GemmP p = {actA, wt0, wt1, nullptr, nullptr, nullptr, nullptr,
               rope, modb, q_txt, q_img, k_cat, v_cat, scales, 4, 6144, 2048, 1};
    gemm2<2><<<dim3(48, 20, 1), 256, 0, stream>>>(p);
  }
  transpose_v<<<dim3(80, 4, 16), dim3(32, 8), 0, stream>>>(v_cat, vT);
  attn_kernel<<<dim3(20, 16, 4), 256, 0, stream>>>(q_txt, q_img, k_cat, vT, Opart, mlbuf);
  attn_merge<<<5120, 256, 0, stream>>>(Opart, mlbuf, ao);
  transpose_w<<<dim3(64, 32), dim3(32, 8), 0, stream>>>(txt_out_w, wt0, 2048, 2048);
  transpose_w<<<dim3(64, 32), dim3(32, 8), 0, stream>>>(img_out_w, wt1, 2048, 2048);
  {
    GemmP p = {ao, wt0, wt1, Cbuf, nullptr, nullptr, nullptr,
               nullptr, nullptr, nullptr, nullptr, nullptr, nullptr, nullptr, 4, 2048, 2048, 2};
    gemm2<0><<<dim3(16, 20, 2), 256, 0, stream>>>(p);
  }
  residual1<<<512, 256, 0, stream>>>((const float4*)txt, (const float4*)Cbuf,
                                     (const float4*)(Cbuf + PSTR), e_txt,
                                     (float4*)out, 512 * 2048 / 4);
  residual1<<<1024, 256, 0, stream>>>((const float4*)img,
                                      (const float4*)(Cbuf + (size_t)512 * 2048),
                                      (const float4*)(Cbuf + PSTR + (size_t)512 * 2048), e_img,
                                      (float4*)out_img, 2048 * 2048 / 4);
  rmsmod_kernel<<<512, 256, 0, stream>>>(out, txt_n2_w, e_txt, 6144, 8192, actA);
  rmsmod_kernel<<<2048, 256, 0, stream>>>(out_img, img_n2_w, e_img, 6144, 8192,
                                          actA + (size_t)512 * 2048);
  transpose_w<<<dim3(256, 32), dim3(32, 8), 0, stream>>>(txt_fc1_w, wt0, 2048, 8192);
  transpose_w<<<dim3(256, 32), dim3(32, 8), 0, stream>>>(img_fc1_w, wt1, 2048, 8192);
  {
    GemmP p = {actA, wt0, wt1, nullptr, actB, txt_fc1_b, img_fc1_b,
               nullptr, nullptr, nullptr, nullptr, nullptr, nullptr, nullptr, 4, 8192, 2048, 1};
    gemm2<1><<<dim3(64, 20, 1), 256, 0, stream>>>(p);
  }
  transpose_w<<<dim3(64, 128), dim3(32, 8), 0, stream>>>(txt_fc2_w, wt0, 8192, 2048);
  transpose_w<<<dim3(64, 128), dim3(32, 8), 0, stream>>>(img_fc2_w, wt1, 8192, 2048);
  {
    GemmP p = {actB, wt0, wt1, Cbuf, nullptr, nullptr, nullptr,
               nullptr, nullptr, nullptr, nullptr, nullptr, nullptr, nullptr, 4, 2048, 8192, 2};
    gemm2<0><<<dim3(16, 20, 2), 256, 0, stream>>>(p);
  }
  residual2<<<512, 256, 0, stream>>>((const float4*)Cbuf, (const float4*)(Cbuf + PSTR),
                                     txt_fc2_b, e_txt, (float4*)out, 512 * 2048 / 4);
  residual2<<<1024, 256, 0, stream>>>((const float4*)(Cbuf + (size_t)512 * 2048),
                                      (const float4*)(Cbuf + PSTR + (size_t)512 * 2048),
                                      img_fc2_b, e_img, (float4*)out_img, 2048 * 2048 / 4);
}

// Round 7
// 918.027 us; speedup vs baseline: 1.0257x; 1.0236x over previous
//
#include <hip/hip_runtime.h>

typedef short short8 __attribute__((ext_vector_type(8)));
typedef float f32x4 __attribute__((ext_vector_type(4)));

__device__ __forceinline__ unsigned short f2bu(float f) {
  unsigned u = __builtin_bit_cast(unsigned, f);
  u += 0x7fffu + ((u >> 16) & 1u);
  return (unsigned short)(u >> 16);
}

__device__ __forceinline__ float b2f(unsigned short b) {
  unsigned u = (unsigned)b << 16;
  return __builtin_bit_cast(float, u);
}

__device__ __forceinline__ float gelu_t(float x) {
  float x3 = x * x * x;
  float t = tanhf(0.7978845608028654f * (x + 0.044715f * x3));
  return 0.5f * x * (1.f + t);
}

__device__ __forceinline__ void gload16(const void* g, void* l) {
  __builtin_amdgcn_global_load_lds(
      (const __attribute__((address_space(1))) void*)g,
      (__attribute__((address_space(3))) void*)l, 16, 0, 0);
}

// ---------------- small prep ----------------
__global__ __launch_bounds__(256) void prep_small(
    const float* __restrict__ vec, const float* __restrict__ sol_t,
    float* __restrict__ silu_vec, float* __restrict__ scales) {
  __shared__ float red[4];
  int t = threadIdx.x;
  float v = (t < 64) ? sol_t[t] : 0.f;
#pragma unroll
  for (int o = 32; o > 0; o >>= 1) v += __shfl_down(v, o);
  if ((t & 63) == 0) red[t >> 6] = v;
  __syncthreads();
  if (t == 0) {
    float m = (red[0] + red[1] + red[2] + red[3]) * (1.f / 64.f);
    m = fmaxf(m, 0.1f);
    const float sc = 0.08838834764831845f;   // 128^-0.5
    const float l2e = 1.4426950408889634f;   // scores computed in log2 domain
    scales[0] = sc * l2e;
    scales[1] = sc / m * l2e;  // s_eff^2 folded into score scale
  }
  for (int k = t; k < 2048; k += 256) {
    float x = vec[k];
    silu_vec[k] = x / (1.f + expf(-x));
  }
}

__global__ __launch_bounds__(256) void mod_kernel(
    const float* __restrict__ S, const float* __restrict__ mw,
    const float* __restrict__ mb, float* __restrict__ modb) {
  int idx = blockIdx.x * 256 + threadIdx.x;  // 16*2048
  int h = idx >> 11, n = idx & 2047;
  int y = n >> 5, x = n & 31;
  float cy = (y + 0.5f) * 0.125f - 0.5f;
  float cx = (x + 0.5f) * 0.25f - 0.5f;
  int y0 = (int)floorf(cy); float fy = cy - (float)y0;
  int x0 = (int)floorf(cx); float fx = cx - (float)x0;
  int y0c = min(max(y0, 0), 7), y1c = min(max(y0 + 1, 0), 7);
  int x0c = min(max(x0, 0), 7), x1c = min(max(x0 + 1, 0), 7);
  float v = (1.f - fy) * ((1.f - fx) * S[y0c * 8 + x0c] + fx * S[y0c * 8 + x1c]) +
            fy * ((1.f - fx) * S[y1c * 8 + x0c] + fx * S[y1c * 8 + x1c]);
  float t = v * mw[h] + mb[h];
  t = fminf(fmaxf(t, -2.f), 2.f);
  modb[idx] = expf(t);
}

__global__ __launch_bounds__(256) void ada_gemv(
    const float* __restrict__ sv,
    const float* __restrict__ Wi, const float* __restrict__ bi,
    const float* __restrict__ Wt, const float* __restrict__ bt,
    float* __restrict__ ei, float* __restrict__ et) {
  __shared__ float red[4][64];
  const float* W = blockIdx.y ? Wt : Wi;
  const float* bb = blockIdx.y ? bt : bi;
  float* e = blockIdx.y ? et : ei;
  int jl = threadIdx.x & 63, ks = threadIdx.x >> 6;
  int j = blockIdx.x * 64 + jl;
  float acc = 0.f;
  int k0 = ks * 512;
#pragma unroll 4
  for (int k = 0; k < 512; ++k) acc += sv[k0 + k] * W[(size_t)(k0 + k) * 12288 + j];
  red[ks][jl] = acc;
  __syncthreads();
  if (ks == 0) e[j] = red[0][jl] + red[1][jl] + red[2][jl] + red[3][jl] + bb[j];
}

// ---------------- RMSNorm + adaLN modulate -> bf16 ----------------
__global__ __launch_bounds__(256) void rmsmod_kernel(
    const float* __restrict__ X, const float* __restrict__ nw,
    const float* __restrict__ e, int sh_off, int sc_off,
    unsigned short* __restrict__ out) {
  __shared__ float red[4];
  int r = blockIdx.x, t = threadIdx.x;
  const float4* xr = reinterpret_cast<const float4*>(X + (size_t)r * 2048);
  float4 v0 = xr[t * 2], v1 = xr[t * 2 + 1];
  float ss = v0.x * v0.x + v0.y * v0.y + v0.z * v0.z + v0.w * v0.w +
             v1.x * v1.x + v1.y * v1.y + v1.z * v1.z + v1.w * v1.w;
#pragma unroll
  for (int o = 32; o > 0; o >>= 1) ss += __shfl_down(ss, o);
  if ((t & 63) == 0) red[t >> 6] = ss;
  __syncthreads();
  float rinv = rsqrtf((red[0] + red[1] + red[2] + red[3]) * (1.f / 2048.f) + 1e-6f);
  int c0 = t * 8;
  float xv[8] = {v0.x, v0.y, v0.z, v0.w, v1.x, v1.y, v1.z, v1.w};
  short8 ov;
#pragma unroll
  for (int i = 0; i < 8; ++i) {
    int c = c0 + i;
    float y = xv[i] * rinv * nw[c] * (1.f + e[sc_off + c]) + e[sh_off + c];
    ov[i] = (short)f2bu(y);
  }
  *reinterpret_cast<short8*>(out + (size_t)r * 2048 + c0) = ov;
}

// ---------------- weight transpose+convert: f32 [K][N] -> bf16 [N][K] ----------------
__global__ __launch_bounds__(256) void transpose_w(
    const float* __restrict__ W, unsigned short* __restrict__ Bt, int K, int N) {
  __shared__ float tile[64][33];
  int n0 = blockIdx.x * 32, k0 = blockIdx.y * 64;
  int tx = threadIdx.x, ty = threadIdx.y;
#pragma unroll
  for (int j = 0; j < 8; ++j)
    tile[ty + j * 8][tx] = W[(size_t)(k0 + ty + j * 8) * N + n0 + tx];
  __syncthreads();
#pragma unroll
  for (int j = 0; j < 4; ++j) {
    int n = ty + j * 8;
    float lo = tile[2 * tx][n], hi = tile[2 * tx + 1][n];
    unsigned pk = (unsigned)f2bu(lo) | ((unsigned)f2bu(hi) << 16);
    *reinterpret_cast<unsigned*>(Bt + (size_t)(n0 + n) * K + k0 + 2 * tx) = pk;
  }
}

__global__ __launch_bounds__(256) void transpose_v(
    const unsigned short* __restrict__ V, unsigned short* __restrict__ Vt) {
  __shared__ unsigned short tile[32][33];
  int h = blockIdx.z;
  int s0 = blockIdx.x * 32, d0 = blockIdx.y * 32;
  int tx = threadIdx.x, ty = threadIdx.y;
  const unsigned short* src = V + (size_t)h * 2560 * 128;
  unsigned short* dst = Vt + (size_t)h * 128 * 2560;
#pragma unroll
  for (int j = 0; j < 32; j += 8)
    tile[ty + j][tx] = src[(size_t)(s0 + ty + j) * 128 + d0 + tx];
  __syncthreads();
#pragma unroll
  for (int j = 0; j < 32; j += 8)
    dst[(size_t)(d0 + ty + j) * 2560 + s0 + tx] = tile[tx][ty + j];
}

// ---------------- batched GEMM (txt rows 0..511, img rows 512..2559) ----------------
struct GemmP {
  const unsigned short *A, *Bt_t, *Bt_i;
  float* C;
  unsigned short* Cb;
  const float *bias_t, *bias_i;
  const float *rope, *modb;
  unsigned short *q_txt, *q_img, *k_cat, *v_cat;
  const float* scales;
  int Mb_t;
  int N, K, KS;
};

template <int EPI>
__global__ __launch_bounds__(256) void gemm2(GemmP p) {
  __shared__ int4 sA[128 * 8];
  __shared__ int4 sB[128 * 8];
  const int NB = gridDim.x, MBT = gridDim.y;
  int nwg = NB * MBT;
  int orig = blockIdx.y * NB + blockIdx.x;
  int qq = nwg >> 3, rr = nwg & 7, xcd = orig & 7, base = orig >> 3;
  int sw = (xcd < rr ? xcd * (qq + 1) : rr * (qq + 1) + (xcd - rr) * qq) + base;
  int bx = sw / MBT, by = sw % MBT;
  const bool is_t = by < p.Mb_t;
  const unsigned short* Bt = is_t ? p.Bt_t : p.Bt_i;
  const int m0 = by * 128, n0 = bx * 128;
  const int z = blockIdx.z;
  const int Kz = p.K / p.KS, kbeg = z * Kz, kend = kbeg + Kz;
  const int tid = threadIdx.x;
  const int w = tid >> 6, l = tid & 63, lr = l & 15, lg = l >> 4;
  const int wm = (w >> 1) * 64, wn = (w & 1) * 64;
  f32x4 acc[4][4] = {};
  const int4* Ag = reinterpret_cast<const int4*>(p.A);
  const int4* Bg = reinterpret_cast<const int4*>(Bt);
  const int K8 = p.K >> 3;
  const short8* pA = reinterpret_cast<const short8*>(sA);
  const short8* pB = reinterpret_cast<const short8*>(sB);
  int srow[4], sch[4];
#pragma unroll
  for (int i = 0; i < 4; ++i) {
    int s = i * 256 + tid;
    srow[i] = s >> 3;
    sch[i] = (s & 7) ^ (srow[i] & 7);
  }
  for (int k0 = kbeg; k0 < kend; k0 += 64) {
    __syncthreads();
    int kc = k0 >> 3;
#pragma unroll
    for (int i = 0; i < 4; ++i) {
      gload16(&Ag[(size_t)(m0 + srow[i]) * K8 + kc + sch[i]], &sA[i * 256 + w * 64]);
      gload16(&Bg[(size_t)(n0 + srow[i]) * K8 + kc + sch[i]], &sB[i * 256 + w * 64]);
    }
    __syncthreads();
#pragma unroll
    for (int kk = 0; kk < 2; ++kk) {
      short8 af[4], bf[4];
#pragma unroll
      for (int m = 0; m < 4; ++m) {
        int row = wm + m * 16 + lr;
        af[m] = pA[row * 8 + ((kk * 4 + lg) ^ (row & 7))];
      }
#pragma unroll
      for (int n = 0; n < 4; ++n) {
        int row = wn + n * 16 + lr;
        bf[n] = pB[row * 8 + ((kk * 4 + lg) ^ (row & 7))];
      }
#pragma unroll
      for (int m = 0; m < 4; ++m)
#pragma unroll
        for (int n = 0; n < 4; ++n)
          acc[m][n] = __builtin_amdgcn_mfma_f32_16x16x32_bf16(af[m], bf[n], acc[m][n], 0, 0, 0);
    }
  }
  if (EPI == 0) {
    float* C = p.C + (size_t)z * MBT * 128 * p.N;
#pragma unroll
    for (int m = 0; m < 4; ++m)
#pragma unroll
      for (int n = 0; n < 4; ++n)
#pragma unroll
        for (int j = 0; j < 4; ++j) {
          int r = m0 + wm + m * 16 + lg * 4 + j;
          int cc = n0 + wn + n * 16 + lr;
          C[(size_t)r * p.N + cc] = acc[m][n][j];
        }
  } else if (EPI == 1) {
    const float* bias = is_t ? p.bias_t : p.bias_i;
#pragma unroll
    for (int n = 0; n < 4; ++n) {
      int cc = n0 + wn + n * 16 + lr;
      float bv = bias[cc];
#pragma unroll
      for (int m = 0; m < 4; ++m)
#pragma unroll
        for (int j = 0; j < 4; ++j) {
          int r = m0 + wm + m * 16 + lg * 4 + j;
          p.Cb[(size_t)r * p.N + cc] = f2bu(gelu_t(acc[m][n][j] + bv));
        }
    }
  } else {
    // qkv epilogue: q pre-scaled (incl. log2e) by scales[0]/scales[1]
    int sel = bx >> 4, h = bx & 15;
#pragma unroll
    for (int n = 0; n < 4; ++n) {
      int d = wn + n * 16 + lr;
#pragma unroll
      for (int m = 0; m < 4; ++m)
#pragma unroll
        for (int j = 0; j < 4; ++j) {
          int r = m0 + wm + m * 16 + lg * 4 + j;
          float v = acc[m][n][j];
          if (is_t) {
            if (sel == 0) p.q_txt[((size_t)h * 512 + r) * 128 + d] = f2bu(v * p.scales[0]);
            else if (sel == 1) p.k_cat[((size_t)h * 2560 + r) * 128 + d] = f2bu(v);
            else p.v_cat[((size_t)h * 2560 + r) * 128 + d] = f2bu(v);
          } else {
            int s = r - 512;
            if (sel == 2) {
              p.v_cat[((size_t)h * 2560 + r) * 128 + d] = f2bu(v);
            } else {
              float c = p.rope[s * 128 + (d & ~1)];
              float sn = p.rope[s * 128 + (d | 1)];
              float part = __shfl_xor(v, 1);
              float vr = (d & 1) ? v * c + part * sn : v * c - part * sn;
              vr *= p.modb[h * 2048 + s];
              if (sel == 0) p.q_img[((size_t)h * 2048 + s) * 128 + d] = f2bu(vr * p.scales[1]);
              else p.k_cat[((size_t)h * 2560 + r) * 128 + d] = f2bu(vr);
            }
          }
        }
    }
  }
}

// ---------------- split-KV flash attention (single-buffer, 48KB, 3 blocks/CU) ---------
// log2-domain scores; defer-max; row-sum l via MFMA ones-column (no shfl sum-reduce).
__global__ __launch_bounds__(256) void attn_kernel(
    const unsigned short* __restrict__ q_txt, const unsigned short* __restrict__ q_img,
    const unsigned short* __restrict__ Kc, const unsigned short* __restrict__ Vt,
    unsigned short* __restrict__ Op, float* __restrict__ ml) {
  __shared__ int4 sK[64 * 16];   // [64 kv][128 d] bf16 = 16KB
  __shared__ int4 sV[128 * 8];   // [128 d][64 kv] bf16 = 16KB
  __shared__ int4 sP[128 * 8];   // [128 q][64 kv] bf16 = 16KB (wave-private rows)
  const int tid = threadIdx.x, w = tid >> 6, l = tid & 63, lr = l & 15, lg = l >> 4;
  const int bx = blockIdx.x, h = blockIdx.y, z = blockIdx.z;
  const bool is_t = bx < 4;
  const int orow = is_t ? bx * 128 : 512 + (bx - 4) * 128;
  const unsigned short* Qp = is_t ? q_txt + ((size_t)h * 512 + bx * 128) * 128
                                  : q_img + ((size_t)h * 2048 + (bx - 4) * 128) * 128;
  short8 aq[2][4];
#pragma unroll
  for (int m = 0; m < 2; ++m)
#pragma unroll
    for (int ds = 0; ds < 4; ++ds) {
      int row = w * 32 + m * 16 + lr;
      aq[m][ds] = *reinterpret_cast<const short8*>(Qp + (size_t)row * 128 + ds * 32 + lg * 8);
    }
  const int4* Kg = reinterpret_cast<const int4*>(Kc + (size_t)h * 2560 * 128);
  const int4* Vg = reinterpret_cast<const int4*>(Vt + (size_t)h * 128 * 2560);
  const short8* pK = reinterpret_cast<const short8*>(sK);
  const short8* pV = reinterpret_cast<const short8*>(sV);
  const short8* pP = reinterpret_cast<const short8*>(sP);
  unsigned short* sPb = reinterpret_cast<unsigned short*>(sP);
  int krow[4], kch[4], vrow[4], vch[4];
#pragma unroll
  for (int i = 0; i < 4; ++i) {
    int s = i * 256 + tid;
    krow[i] = s >> 4; kch[i] = (s & 15) ^ (krow[i] & 7);
    vrow[i] = s >> 3; vch[i] = (s & 7) ^ (vrow[i] & 7);
  }
  // ones fragment for l-accumulating MFMA (bf16 1.0 = 0x3F80)
  short8 ones8;
#pragma unroll
  for (int i = 0; i < 8; ++i) ones8[i] = (short)0x3F80;

  f32x4 oacc[2][8] = {};
  f32x4 oacc_l[2] = {};
  float m_run[2][4];
#pragma unroll
  for (int m = 0; m < 2; ++m)
#pragma unroll
    for (int j = 0; j < 4; ++j) m_run[m][j] = -1e30f;

  for (int kt = z * 10; kt < z * 10 + 10; ++kt) {
    __syncthreads();
#pragma unroll
    for (int i = 0; i < 4; ++i) {
      gload16(&Kg[(size_t)(kt * 64 + krow[i]) * 16 + kch[i]], &sK[i * 256 + w * 64]);
      gload16(&Vg[(size_t)vrow[i] * 320 + kt * 8 + vch[i]], &sV[i * 256 + w * 64]);
    }
    __syncthreads();
    f32x4 sacc[2][4] = {};
    __builtin_amdgcn_s_setprio(1);
#pragma unroll
    for (int ds = 0; ds < 4; ++ds) {
      short8 bk[4];
#pragma unroll
      for (int n = 0; n < 4; ++n) {
        int row = n * 16 + lr;
        bk[n] = pK[row * 16 + ((ds * 4 + lg) ^ (row & 7))];
      }
#pragma unroll
      for (int m = 0; m < 2; ++m)
#pragma unroll
        for (int n = 0; n < 4; ++n)
          sacc[m][n] = __builtin_amdgcn_mfma_f32_16x16x32_bf16(aq[m][ds], bk[n], sacc[m][n], 0, 0, 0);
    }
    __builtin_amdgcn_s_setprio(0);
    // softmax (log2 domain, defer-max); P written fused; l comes from PV ones-column
    float corr_[2][4];
    bool grow_any = false;
#pragma unroll
    for (int m = 0; m < 2; ++m)
#pragma unroll
      for (int j = 0; j < 4; ++j) {
        float mx = fmaxf(fmaxf(sacc[m][0][j], sacc[m][1][j]),
                         fmaxf(sacc[m][2][j], sacc[m][3][j]));
        mx = fmaxf(mx, __shfl_xor(mx, 1));
        mx = fmaxf(mx, __shfl_xor(mx, 2));
        mx = fmaxf(mx, __shfl_xor(mx, 4));
        mx = fmaxf(mx, __shfl_xor(mx, 8));
        bool grow = mx > m_run[m][j] + 11.0f;
        grow_any |= grow;
        float mn = grow ? mx : m_run[m][j];
        corr_[m][j] = exp2f(m_run[m][j] - mn);  // == 1.0 when deferred
        m_run[m][j] = mn;
        int prow = w * 32 + m * 16 + lg * 4 + j;
#pragma unroll
        for (int n = 0; n < 4; ++n) {
          float pp = exp2f(sacc[m][n][j] - mn);
          int col = n * 16 + lr;
          sPb[prow * 64 + (((col >> 3) ^ (prow & 7)) << 3) + (col & 7)] = f2bu(pp);
        }
      }
    if (__any(grow_any)) {
#pragma unroll
      for (int m = 0; m < 2; ++m) {
#pragma unroll
        for (int n = 0; n < 8; ++n)
#pragma unroll
          for (int j = 0; j < 4; ++j) oacc[m][n][j] *= corr_[m][j];
#pragma unroll
        for (int j = 0; j < 4; ++j) oacc_l[m][j] *= corr_[m][j];
      }
    }
    // PV (P rows wave-private: no barrier). Extra ones-MFMA accumulates row sums.
    __builtin_amdgcn_s_setprio(1);
#pragma unroll
    for (int kk = 0; kk < 2; ++kk) {
      short8 ap[2], bv[8];
#pragma unroll
      for (int m = 0; m < 2; ++m) {
        int row = w * 32 + m * 16 + lr;
        ap[m] = pP[row * 8 + ((kk * 4 + lg) ^ (row & 7))];
      }
#pragma unroll
      for (int n = 0; n < 8; ++n) {
        int row = n * 16 + lr;
        bv[n] = pV[row * 8 + ((kk * 4 + lg) ^ (row & 7))];
      }
#pragma unroll
      for (int m = 0; m < 2; ++m) {
#pragma unroll
        for (int n = 0; n < 8; ++n)
          oacc[m][n] = __builtin_amdgcn_mfma_f32_16x16x32_bf16(ap[m], bv[n], oacc[m][n], 0, 0, 0);
        oacc_l[m] = __builtin_amdgcn_mfma_f32_16x16x32_bf16(ap[m], ones8, oacc_l[m], 0, 0, 0);
      }
    }
    __builtin_amdgcn_s_setprio(0);
  }
  const size_t zbase = (size_t)z * 40960 + (size_t)h * 2560 + orow;
#pragma unroll
  for (int m = 0; m < 2; ++m)
#pragma unroll
    for (int j = 0; j < 4; ++j) {
      int row = w * 32 + m * 16 + lg * 4 + j;
#pragma unroll
      for (int n = 0; n < 8; ++n)
        Op[(zbase + row) * 128 + n * 16 + lr] = f2bu(oacc[m][n][j]);
      if (lr == 0) {
        ml[(zbase + row) * 2] = m_run[m][j];
        ml[(zbase + row) * 2 + 1] = oacc_l[m][j];
      }
    }
}

// merge 4 KV-chunk partials (log2-domain LSE combine) -> ao[r][h*128+d] bf16
__global__ __launch_bounds__(256) void attn_merge(
    const unsigned short* __restrict__ Op, const float* __restrict__ ml,
    unsigned short* __restrict__ ao) {
  int gid = blockIdx.x * 256 + threadIdx.x;  // 40960 rows * 32 threads
  int rid = gid >> 5, d0 = (gid & 31) * 4;
  int h = rid / 2560;
  int r = rid - h * 2560;
  float M = -1e30f;
#pragma unroll
  for (int z = 0; z < 4; ++z) M = fmaxf(M, ml[((size_t)z * 40960 + rid) * 2]);
  float L = 0.f, o0 = 0.f, o1 = 0.f, o2 = 0.f, o3 = 0.f;
#pragma unroll
  for (int z = 0; z < 4; ++z) {
    size_t sidx = (size_t)z * 40960 + rid;
    float mz = ml[sidx * 2], lz = ml[sidx * 2 + 1];
    float wgt = exp2f(mz - M);
    L += wgt * lz;
    ushort4 v = *reinterpret_cast<const ushort4*>(Op + sidx * 128 + d0);
    o0 += wgt * b2f(v.x); o1 += wgt * b2f(v.y);
    o2 += wgt * b2f(v.z); o3 += wgt * b2f(v.w);
  }
  float inv = 1.f / L;
  ushort4 ov;
  ov.x = f2bu(o0 * inv); ov.y = f2bu(o1 * inv);
  ov.z = f2bu(o2 * inv); ov.w = f2bu(o3 * inv);
  *reinterpret_cast<ushort4*>(ao + (size_t)r * 2048 + h * 128 + d0) = ov;
}

// ---------------- residuals (sum 2 split-K partials) ----------------
__global__ __launch_bounds__(256) void residual1(
    const float4* __restrict__ X, const float4* __restrict__ P0,
    const float4* __restrict__ P1, const float* __restrict__ e,
    float4* __restrict__ out, int total4) {
  int stride = gridDim.x * 256;
  for (int i = blockIdx.x * 256 + threadIdx.x; i < total4; i += stride) {
    int c = (i * 4) & 2047;
    float4 g = *reinterpret_cast<const float4*>(e + 4096 + c);
    float4 x = X[i], p0 = P0[i], p1 = P1[i], o;
    o.x = x.x + g.x * (p0.x + p1.x); o.y = x.y + g.y * (p0.y + p1.y);
    o.z = x.z + g.z * (p0.z + p1.z); o.w = x.w + g.w * (p0.w + p1.w);
    out[i] = o;
  }
}

__global__ __launch_bounds__(256) void residual2(
    const float4* __restrict__ P0, const float4* __restrict__ P1,
    const float* __restrict__ b2, const float* __restrict__ e,
    float4* __restrict__ out, int total4) {
  int stride = gridDim.x * 256;
  for (int i = blockIdx.x * 256 + threadIdx.x; i < total4; i += stride) {
    int c = (i * 4) & 2047;
    float4 g = *reinterpret_cast<const float4*>(e + 10240 + c);
    float4 bb = *reinterpret_cast<const float4*>(b2 + c);
    float4 p0 = P0[i], p1 = P1[i], o = out[i];
    o.x += g.x * (p0.x + p1.x + bb.x); o.y += g.y * (p0.y + p1.y + bb.y);
    o.z += g.z * (p0.z + p1.z + bb.z); o.w += g.w * (p0.w + p1.w + bb.w);
    out[i] = o;
  }
}

extern "C" void kernel_launch(void* const* d_in, const int* in_sizes, int n_in,
                              void* d_out, int out_size, void* d_ws, size_t ws_size,
                              hipStream_t stream) {
  (void)in_sizes; (void)n_in; (void)out_size; (void)ws_size;
  const float* txt = (const float*)d_in[0];
  const float* img = (const float*)d_in[1];
  const float* vec = (const float*)d_in[2];
  const float* rope = (const float*)d_in[3];
  const float* sol_t = (const float*)d_in[4];
  const float* sol_s = (const float*)d_in[5];
  const float* ada_img_w = (const float*)d_in[6];
  const float* ada_img_b = (const float*)d_in[7];
  const float* ada_img_nw = (const float*)d_in[8];
  const float* ada_txt_w = (const float*)d_in[9];
  const float* ada_txt_b = (const float*)d_in[10];
  const float* ada_txt_nw = (const float*)d_in[11];
  const float* txt_qkv_w = (const float*)d_in[12];
  const float* img_qkv_w = (const float*)d_in[13];
  const float* txt_out_w = (const float*)d_in[14];
  const float* img_out_w = (const float*)d_in[15];
  const float* mod_w = (const float*)d_in[16];
  const float* mod_b = (const float*)d_in[17];
  const float* img_n2_w = (const float*)d_in[18];
  const float* txt_n2_w = (const float*)d_in[19];
  const float* img_fc1_w = (const float*)d_in[20];
  const float* img_fc1_b = (const float*)d_in[21];
  const float* img_fc2_w = (const float*)d_in[22];
  const float* img_fc2_b = (const float*)d_in[23];
  const float* txt_fc1_w = (const float*)d_in[24];
  const float* txt_fc1_b = (const float*)d_in[25];
  const float* txt_fc2_w = (const float*)d_in[26];
  const float* txt_fc2_b = (const float*)d_in[27];
  float* out = (float*)d_out;
  float* out_img = out + (size_t)512 * 2048;
  char* ws = (char*)d_ws;

  const size_t MB = 1 << 20;
  float* silu_vec = (float*)(ws + 0);
  float* scales = (float*)(ws + 8192);
  float* modb = (float*)(ws + 16384);
  float* e_img = (float*)(ws + 147456);
  float* e_txt = (float*)(ws + 196608);
  unsigned short* wt0 = (unsigned short*)(ws + 1 * MB);    // 32MB txt weights
  unsigned short* wt1 = (unsigned short*)(ws + 33 * MB);   // 32MB img weights
  unsigned short* Opart = (unsigned short*)(ws + 1 * MB);  // 40MB (overlays weights, dead then)
  float* mlbuf = (float*)(ws + 42 * MB);                   // 1.25MB
  unsigned short* actA = (unsigned short*)(ws + 65 * MB);  // [2560][2048] bf16, 10MB
  char* attn_base = ws + 75 * MB;                          // 50MB region
  unsigned short* q_txt = (unsigned short*)(attn_base);
  unsigned short* q_img = (unsigned short*)(attn_base + 2 * MB);
  unsigned short* k_cat = (unsigned short*)(attn_base + 10 * MB);
  unsigned short* v_cat = (unsigned short*)(attn_base + 20 * MB);
  unsigned short* vT = (unsigned short*)(attn_base + 30 * MB);
  unsigned short* ao = (unsigned short*)(attn_base + 40 * MB);
  unsigned short* actB = (unsigned short*)attn_base;  // [2560][8192] bf16 (MLP phase)
  float* Cbuf = (float*)(ws + 125 * MB);  // 2 partials x [2560][2048] f32 = 40MB
  const size_t PSTR = (size_t)2560 * 2048;

  prep_small<<<1, 256, 0, stream>>>(vec, sol_t, silu_vec, scales);
  mod_kernel<<<128, 256, 0, stream>>>(sol_s, mod_w, mod_b, modb);
  ada_gemv<<<dim3(192, 2), 256, 0, stream>>>(silu_vec, ada_img_w, ada_img_b,
                                             ada_txt_w, ada_txt_b, e_img, e_txt);
  rmsmod_kernel<<<512, 256, 0, stream>>>(txt, ada_txt_nw, e_txt, 0, 2048, actA);
  rmsmod_kernel<<<2048, 256, 0, stream>>>(img, ada_img_nw, e_img, 0, 2048,
                                          actA + (size_t)512 * 2048);
  transpose_w<<<dim3(192, 32), dim3(32, 8), 0, stream>>>(txt_qkv_w, wt0, 2048, 6144);
  transpose_w<<<dim3(192, 32), dim3(32, 8), 0, stream>>>(img_qkv_w, wt1, 2048, 6144);
  {
    GemmP p = {actA, wt0, wt1, nullptr, nullptr, nullptr, nullptr,
               rope, modb, q_txt, q_img, k_cat, v_cat, scales, 4, 6144, 2048, 1};
    gemm2<2><<<dim3(48, 20, 1), 256, 0, stream>>>(p);
  }
  transpose_v<<<dim3(80, 4, 16), dim3(32, 8), 0, stream>>>(v_cat, vT);
  attn_kernel<<<dim3(20, 16, 4), 256, 0, stream>>>(q_txt, q_img, k_cat, vT, Opart, mlbuf);
  attn_merge<<<5120, 256, 0, stream>>>(Opart, mlbuf, ao);
  transpose_w<<<dim3(64, 32), dim3(32, 8), 0, stream>>>(txt_out_w, wt0, 2048, 2048);
  transpose_w<<<dim3(64, 32), dim3(32, 8), 0, stream>>>(img_out_w, wt1, 2048, 2048);
  {
    GemmP p = {ao, wt0, wt1, Cbuf, nullptr, nullptr, nullptr,
               nullptr, nullptr, nullptr, nullptr, nullptr, nullptr, nullptr, 4, 2048, 2048, 2};
    gemm2<0><<<dim3(16, 20, 2), 256, 0, stream>>>(p);
  }
  residual1<<<512, 256, 0, stream>>>((const float4*)txt, (const float4*)Cbuf,
                                     (const float4*)(Cbuf + PSTR), e_txt,
                                     (float4*)out, 512 * 2048 / 4);
  residual1<<<1024, 256, 0, stream>>>((const float4*)img,
                                      (const float4*)(Cbuf + (size_t)512 * 2048),
                                      (const float4*)(Cbuf + PSTR + (size_t)512 * 2048), e_img,
                                      (float4*)out_img, 2048 * 2048 / 4);
  rmsmod_kernel<<<512, 256, 0, stream>>>(out, txt_n2_w, e_txt, 6144, 8192, actA);
  rmsmod_kernel<<<2048, 256, 0, stream>>>(out_img, img_n2_w, e_img, 6144, 8192,
                                          actA + (size_t)512 * 2048);
  transpose_w<<<dim3(256, 32), dim3(32, 8), 0, stream>>>(txt_fc1_w, wt0, 2048, 8192);
  transpose_w<<<dim3(256, 32), dim3(32, 8), 0, stream>>>(img_fc1_w, wt1, 2048, 8192);
  {
    GemmP p = {actA, wt0, wt1, nullptr, actB, txt_fc1_b, img_fc1_b,
               nullptr, nullptr, nullptr, nullptr, nullptr, nullptr, nullptr, 4, 8192, 2048, 1};
    gemm2<1><<<dim3(64, 20, 1), 256, 0, stream>>>(p);
  }
  transpose_w<<<dim3(64, 128), dim3(32, 8), 0, stream>>>(txt_fc2_w, wt0, 8192, 2048);
  transpose_w<<<dim3(64, 128), dim3(32, 8), 0, stream>>>(img_fc2_w, wt1, 8192, 2048);
  {
    GemmP p = {actB, wt0, wt1, Cbuf, nullptr, nullptr, nullptr,
               nullptr, nullptr, nullptr, nullptr, nullptr, nullptr, nullptr, 4, 2048, 8192, 2};
    gemm2<0><<<dim3(16, 20, 2), 256, 0, stream>>>(p);
  }
  residual2<<<512, 256, 0, stream>>>((const float4*)Cbuf, (const float4*)(Cbuf + PSTR),
                                     txt_fc2_b, e_txt, (float4*)out, 512 * 2048 / 4);
  residual2<<<1024, 256, 0, stream>>>((const float4*)(Cbuf + (size_t)512 * 2048),
                                      (const float4*)(Cbuf + PSTR + (size_t)512 * 2048),
                                      img_fc2_b, e_img, (float4*)out_img, 2048 * 2048 / 4);
}

// Round 8
// 899.508 us; speedup vs baseline: 1.0468x; 1.0206x over previous
//
#include <hip/hip_runtime.h>

typedef short short8 __attribute__((ext_vector_type(8)));
typedef float f32x4 __attribute__((ext_vector_type(4)));

__device__ __forceinline__ unsigned short f2bu(float f) {
  unsigned u = __builtin_bit_cast(unsigned, f);
  u += 0x7fffu + ((u >> 16) & 1u);
  return (unsigned short)(u >> 16);
}

__device__ __forceinline__ float b2f(unsigned short b) {
  unsigned u = (unsigned)b << 16;
  return __builtin_bit_cast(float, u);
}

__device__ __forceinline__ float gelu_t(float x) {
  float x3 = x * x * x;
  float t = tanhf(0.7978845608028654f * (x + 0.044715f * x3));
  return 0.5f * x * (1.f + t);
}

__device__ __forceinline__ void gload16(const void* g, void* l) {
  __builtin_amdgcn_global_load_lds(
      (const __attribute__((address_space(1))) void*)g,
      (__attribute__((address_space(3))) void*)l, 16, 0, 0);
}

// ---------------- small prep ----------------
__global__ __launch_bounds__(256) void prep_small(
    const float* __restrict__ vec, const float* __restrict__ sol_t,
    float* __restrict__ silu_vec, float* __restrict__ scales) {
  __shared__ float red[4];
  int t = threadIdx.x;
  float v = (t < 64) ? sol_t[t] : 0.f;
#pragma unroll
  for (int o = 32; o > 0; o >>= 1) v += __shfl_down(v, o);
  if ((t & 63) == 0) red[t >> 6] = v;
  __syncthreads();
  if (t == 0) {
    float m = (red[0] + red[1] + red[2] + red[3]) * (1.f / 64.f);
    m = fmaxf(m, 0.1f);
    const float sc = 0.08838834764831845f;   // 128^-0.5
    const float l2e = 1.4426950408889634f;   // scores computed in log2 domain
    scales[0] = sc * l2e;
    scales[1] = sc / m * l2e;  // s_eff^2 folded into score scale
  }
  for (int k = t; k < 2048; k += 256) {
    float x = vec[k];
    silu_vec[k] = x / (1.f + expf(-x));
  }
}

__global__ __launch_bounds__(256) void mod_kernel(
    const float* __restrict__ S, const float* __restrict__ mw,
    const float* __restrict__ mb, float* __restrict__ modb) {
  int idx = blockIdx.x * 256 + threadIdx.x;  // 16*2048
  int h = idx >> 11, n = idx & 2047;
  int y = n >> 5, x = n & 31;
  float cy = (y + 0.5f) * 0.125f - 0.5f;
  float cx = (x + 0.5f) * 0.25f - 0.5f;
  int y0 = (int)floorf(cy); float fy = cy - (float)y0;
  int x0 = (int)floorf(cx); float fx = cx - (float)x0;
  int y0c = min(max(y0, 0), 7), y1c = min(max(y0 + 1, 0), 7);
  int x0c = min(max(x0, 0), 7), x1c = min(max(x0 + 1, 0), 7);
  float v = (1.f - fy) * ((1.f - fx) * S[y0c * 8 + x0c] + fx * S[y0c * 8 + x1c]) +
            fy * ((1.f - fx) * S[y1c * 8 + x0c] + fx * S[y1c * 8 + x1c]);
  float t = v * mw[h] + mb[h];
  t = fminf(fmaxf(t, -2.f), 2.f);
  modb[idx] = expf(t);
}

__global__ __launch_bounds__(256) void ada_gemv(
    const float* __restrict__ sv,
    const float* __restrict__ Wi, const float* __restrict__ bi,
    const float* __restrict__ Wt, const float* __restrict__ bt,
    float* __restrict__ ei, float* __restrict__ et) {
  __shared__ float red[4][64];
  const float* W = blockIdx.y ? Wt : Wi;
  const float* bb = blockIdx.y ? bt : bi;
  float* e = blockIdx.y ? et : ei;
  int jl = threadIdx.x & 63, ks = threadIdx.x >> 6;
  int j = blockIdx.x * 64 + jl;
  float acc = 0.f;
  int k0 = ks * 512;
#pragma unroll 4
  for (int k = 0; k < 512; ++k) acc += sv[k0 + k] * W[(size_t)(k0 + k) * 12288 + j];
  red[ks][jl] = acc;
  __syncthreads();
  if (ks == 0) e[j] = red[0][jl] + red[1][jl] + red[2][jl] + red[3][jl] + bb[j];
}

// ---------------- RMSNorm + adaLN modulate -> bf16 ----------------
__global__ __launch_bounds__(256) void rmsmod_kernel(
    const float* __restrict__ X, const float* __restrict__ nw,
    const float* __restrict__ e, int sh_off, int sc_off,
    unsigned short* __restrict__ out) {
  __shared__ float red[4];
  int r = blockIdx.x, t = threadIdx.x;
  const float4* xr = reinterpret_cast<const float4*>(X + (size_t)r * 2048);
  float4 v0 = xr[t * 2], v1 = xr[t * 2 + 1];
  float ss = v0.x * v0.x + v0.y * v0.y + v0.z * v0.z + v0.w * v0.w +
             v1.x * v1.x + v1.y * v1.y + v1.z * v1.z + v1.w * v1.w;
#pragma unroll
  for (int o = 32; o > 0; o >>= 1) ss += __shfl_down(ss, o);
  if ((t & 63) == 0) red[t >> 6] = ss;
  __syncthreads();
  float rinv = rsqrtf((red[0] + red[1] + red[2] + red[3]) * (1.f / 2048.f) + 1e-6f);
  int c0 = t * 8;
  float xv[8] = {v0.x, v0.y, v0.z, v0.w, v1.x, v1.y, v1.z, v1.w};
  short8 ov;
#pragma unroll
  for (int i = 0; i < 8; ++i) {
    int c = c0 + i;
    float y = xv[i] * rinv * nw[c] * (1.f + e[sc_off + c]) + e[sh_off + c];
    ov[i] = (short)f2bu(y);
  }
  *reinterpret_cast<short8*>(out + (size_t)r * 2048 + c0) = ov;
}

// ---------------- weight transpose+convert: f32 [K][N] -> bf16 [N][K] ----------------
// 64k x 32n tiles; 16B packed stores (8 bf16 per lane).
__global__ __launch_bounds__(256) void transpose_w(
    const float* __restrict__ W, unsigned short* __restrict__ Bt, int K, int N) {
  __shared__ float tile[64][33];
  int n0 = blockIdx.x * 32, k0 = blockIdx.y * 64;
  int tid = threadIdx.x;
  int tx = tid & 31, ty = tid >> 5;
#pragma unroll
  for (int j = 0; j < 8; ++j)
    tile[ty + j * 8][tx] = W[(size_t)(k0 + ty + j * 8) * N + n0 + tx];
  __syncthreads();
  int n = tid >> 3, ks = (tid & 7) * 8;
  unsigned pk[4];
#pragma unroll
  for (int i = 0; i < 4; ++i) {
    float lo = tile[ks + 2 * i][n], hi = tile[ks + 2 * i + 1][n];
    pk[i] = (unsigned)f2bu(lo) | ((unsigned)f2bu(hi) << 16);
  }
  int4 ov = make_int4(pk[0], pk[1], pk[2], pk[3]);
  *reinterpret_cast<int4*>(Bt + (size_t)(n0 + n) * K + k0 + ks) = ov;
}

__global__ __launch_bounds__(256) void transpose_v(
    const unsigned short* __restrict__ V, unsigned short* __restrict__ Vt) {
  __shared__ unsigned short tile[32][33];
  int h = blockIdx.z;
  int s0 = blockIdx.x * 32, d0 = blockIdx.y * 32;
  int tx = threadIdx.x, ty = threadIdx.y;
  const unsigned short* src = V + (size_t)h * 2560 * 128;
  unsigned short* dst = Vt + (size_t)h * 128 * 2560;
#pragma unroll
  for (int j = 0; j < 32; j += 8)
    tile[ty + j][tx] = src[(size_t)(s0 + ty + j) * 128 + d0 + tx];
  __syncthreads();
#pragma unroll
  for (int j = 0; j < 32; j += 8)
    dst[(size_t)(d0 + ty + j) * 2560 + s0 + tx] = tile[tx][ty + j];
}

// ---------------- batched GEMM (txt rows 0..511, img rows 512..2559) ----------------
struct GemmP {
  const unsigned short *A, *Bt_t, *Bt_i;
  float* C;
  unsigned short* Cb;
  const float *bias_t, *bias_i;
  const float *rope, *modb;
  unsigned short *q_txt, *q_img, *k_cat, *v_cat;
  const float* scales;
  int Mb_t;
  int N, K, KS;
};

template <int EPI>
__global__ __launch_bounds__(256) void gemm2(GemmP p) {
  __shared__ int4 sA[128 * 8];
  __shared__ int4 sB[128 * 8];
  const int NB = gridDim.x, MBT = gridDim.y;
  int nwg = NB * MBT;
  int orig = blockIdx.y * NB + blockIdx.x;
  int qq = nwg >> 3, rr = nwg & 7, xcd = orig & 7, base = orig >> 3;
  int sw = (xcd < rr ? xcd * (qq + 1) : rr * (qq + 1) + (xcd - rr) * qq) + base;
  int bx = sw / MBT, by = sw % MBT;
  const bool is_t = by < p.Mb_t;
  const unsigned short* Bt = is_t ? p.Bt_t : p.Bt_i;
  const int m0 = by * 128, n0 = bx * 128;
  const int z = blockIdx.z;
  const int Kz = p.K / p.KS, kbeg = z * Kz, kend = kbeg + Kz;
  const int tid = threadIdx.x;
  const int w = tid >> 6, l = tid & 63, lr = l & 15, lg = l >> 4;
  const int wm = (w >> 1) * 64, wn = (w & 1) * 64;
  f32x4 acc[4][4] = {};
  const int4* Ag = reinterpret_cast<const int4*>(p.A);
  const int4* Bg = reinterpret_cast<const int4*>(Bt);
  const int K8 = p.K >> 3;
  const short8* pA = reinterpret_cast<const short8*>(sA);
  const short8* pB = reinterpret_cast<const short8*>(sB);
  int srow[4], sch[4];
#pragma unroll
  for (int i = 0; i < 4; ++i) {
    int s = i * 256 + tid;
    srow[i] = s >> 3;
    sch[i] = (s & 7) ^ (srow[i] & 7);
  }
  for (int k0 = kbeg; k0 < kend; k0 += 64) {
    __syncthreads();
    int kc = k0 >> 3;
#pragma unroll
    for (int i = 0; i < 4; ++i) {
      gload16(&Ag[(size_t)(m0 + srow[i]) * K8 + kc + sch[i]], &sA[i * 256 + w * 64]);
      gload16(&Bg[(size_t)(n0 + srow[i]) * K8 + kc + sch[i]], &sB[i * 256 + w * 64]);
    }
    __syncthreads();
#pragma unroll
    for (int kk = 0; kk < 2; ++kk) {
      short8 af[4], bf[4];
#pragma unroll
      for (int m = 0; m < 4; ++m) {
        int row = wm + m * 16 + lr;
        af[m] = pA[row * 8 + ((kk * 4 + lg) ^ (row & 7))];
      }
#pragma unroll
      for (int n = 0; n < 4; ++n) {
        int row = wn + n * 16 + lr;
        bf[n] = pB[row * 8 + ((kk * 4 + lg) ^ (row & 7))];
      }
#pragma unroll
      for (int m = 0; m < 4; ++m)
#pragma unroll
        for (int n = 0; n < 4; ++n)
          acc[m][n] = __builtin_amdgcn_mfma_f32_16x16x32_bf16(af[m], bf[n], acc[m][n], 0, 0, 0);
    }
  }
  if (EPI == 0) {
    float* C = p.C + (size_t)z * MBT * 128 * p.N;
#pragma unroll
    for (int m = 0; m < 4; ++m)
#pragma unroll
      for (int n = 0; n < 4; ++n)
#pragma unroll
        for (int j = 0; j < 4; ++j) {
          int r = m0 + wm + m * 16 + lg * 4 + j;
          int cc = n0 + wn + n * 16 + lr;
          C[(size_t)r * p.N + cc] = acc[m][n][j];
        }
  } else if (EPI == 1) {
    const float* bias = is_t ? p.bias_t : p.bias_i;
#pragma unroll
    for (int n = 0; n < 4; ++n) {
      int cc = n0 + wn + n * 16 + lr;
      float bv = bias[cc];
#pragma unroll
      for (int m = 0; m < 4; ++m)
#pragma unroll
        for (int j = 0; j < 4; ++j) {
          int r = m0 + wm + m * 16 + lg * 4 + j;
          p.Cb[(size_t)r * p.N + cc] = f2bu(gelu_t(acc[m][n][j] + bv));
        }
    }
  } else {
    // qkv epilogue: q pre-scaled (incl. log2e) by scales[0]/scales[1]
    int sel = bx >> 4, h = bx & 15;
#pragma unroll
    for (int n = 0; n < 4; ++n) {
      int d = wn + n * 16 + lr;
#pragma unroll
      for (int m = 0; m < 4; ++m)
#pragma unroll
        for (int j = 0; j < 4; ++j) {
          int r = m0 + wm + m * 16 + lg * 4 + j;
          float v = acc[m][n][j];
          if (is_t) {
            if (sel == 0) p.q_txt[((size_t)h * 512 + r) * 128 + d] = f2bu(v * p.scales[0]);
            else if (sel == 1) p.k_cat[((size_t)h * 2560 + r) * 128 + d] = f2bu(v);
            else p.v_cat[((size_t)h * 2560 + r) * 128 + d] = f2bu(v);
          } else {
            int s = r - 512;
            if (sel == 2) {
              p.v_cat[((size_t)h * 2560 + r) * 128 + d] = f2bu(v);
            } else {
              float c = p.rope[s * 128 + (d & ~1)];
              float sn = p.rope[s * 128 + (d | 1)];
              float part = __shfl_xor(v, 1);
              float vr = (d & 1) ? v * c + part * sn : v * c - part * sn;
              vr *= p.modb[h * 2048 + s];
              if (sel == 0) p.q_img[((size_t)h * 2048 + s) * 128 + d] = f2bu(vr * p.scales[1]);
              else p.k_cat[((size_t)h * 2560 + r) * 128 + d] = f2bu(vr);
            }
          }
        }
    }
  }
}

// ---------------- split-KV flash attention (QBLK=64, 40KB LDS, 4 blocks/CU) ----------
// grid (40, 16, 4). Each wave owns 16 q-rows. log2-domain; defer-max;
// l via MFMA ones-column.
__global__ __launch_bounds__(256, 4) void attn_kernel(
    const unsigned short* __restrict__ q_txt, const unsigned short* __restrict__ q_img,
    const unsigned short* __restrict__ Kc, const unsigned short* __restrict__ Vt,
    unsigned short* __restrict__ Op, float* __restrict__ ml) {
  __shared__ int4 sK[64 * 16];  // [64 kv][128 d] bf16 = 16KB
  __shared__ int4 sV[128 * 8];  // [128 d][64 kv] bf16 = 16KB
  __shared__ int4 sP[64 * 8];   // [64 q][64 kv] bf16 = 8KB (wave-private rows)
  const int tid = threadIdx.x, w = tid >> 6, l = tid & 63, lr = l & 15, lg = l >> 4;
  const int bx = blockIdx.x, h = blockIdx.y, z = blockIdx.z;
  const bool is_t = bx < 8;
  const int orow = is_t ? bx * 64 : 512 + (bx - 8) * 64;
  const unsigned short* Qp = is_t ? q_txt + ((size_t)h * 512 + bx * 64) * 128
                                  : q_img + ((size_t)h * 2048 + (bx - 8) * 64) * 128;
  short8 aq[4];
#pragma unroll
  for (int ds = 0; ds < 4; ++ds) {
    int row = w * 16 + lr;
    aq[ds] = *reinterpret_cast<const short8*>(Qp + (size_t)row * 128 + ds * 32 + lg * 8);
  }
  const int4* Kg = reinterpret_cast<const int4*>(Kc + (size_t)h * 2560 * 128);
  const int4* Vg = reinterpret_cast<const int4*>(Vt + (size_t)h * 128 * 2560);
  const short8* pK = reinterpret_cast<const short8*>(sK);
  const short8* pV = reinterpret_cast<const short8*>(sV);
  const short8* pP = reinterpret_cast<const short8*>(sP);
  unsigned short* sPb = reinterpret_cast<unsigned short*>(sP);
  int krow[4], kch[4], vrow[4], vch[4];
#pragma unroll
  for (int i = 0; i < 4; ++i) {
    int s = i * 256 + tid;
    krow[i] = s >> 4; kch[i] = (s & 15) ^ (krow[i] & 7);
    vrow[i] = s >> 3; vch[i] = (s & 7) ^ (vrow[i] & 7);
  }
  short8 ones8;
#pragma unroll
  for (int i = 0; i < 8; ++i) ones8[i] = (short)0x3F80;

  f32x4 oacc[8] = {};
  f32x4 oacc_l = {};
  float m_run[4];
#pragma unroll
  for (int j = 0; j < 4; ++j) m_run[j] = -1e30f;

  for (int kt = z * 10; kt < z * 10 + 10; ++kt) {
    __syncthreads();
#pragma unroll
    for (int i = 0; i < 4; ++i) {
      gload16(&Kg[(size_t)(kt * 64 + krow[i]) * 16 + kch[i]], &sK[i * 256 + w * 64]);
      gload16(&Vg[(size_t)vrow[i] * 320 + kt * 8 + vch[i]], &sV[i * 256 + w * 64]);
    }
    __syncthreads();
    f32x4 sacc[4] = {};
    __builtin_amdgcn_s_setprio(1);
#pragma unroll
    for (int ds = 0; ds < 4; ++ds) {
      short8 bk[4];
#pragma unroll
      for (int n = 0; n < 4; ++n) {
        int row = n * 16 + lr;
        bk[n] = pK[row * 16 + ((ds * 4 + lg) ^ (row & 7))];
      }
#pragma unroll
      for (int n = 0; n < 4; ++n)
        sacc[n] = __builtin_amdgcn_mfma_f32_16x16x32_bf16(aq[ds], bk[n], sacc[n], 0, 0, 0);
    }
    __builtin_amdgcn_s_setprio(0);
    // softmax (log2 domain, defer-max); P write fused; l via PV ones-column
    float corr_[4];
    bool grow_any = false;
#pragma unroll
    for (int j = 0; j < 4; ++j) {
      float mx = fmaxf(fmaxf(sacc[0][j], sacc[1][j]), fmaxf(sacc[2][j], sacc[3][j]));
      mx = fmaxf(mx, __shfl_xor(mx, 1));
      mx = fmaxf(mx, __shfl_xor(mx, 2));
      mx = fmaxf(mx, __shfl_xor(mx, 4));
      mx = fmaxf(mx, __shfl_xor(mx, 8));
      bool grow = mx > m_run[j] + 11.0f;
      grow_any |= grow;
      float mn = grow ? mx : m_run[j];
      corr_[j] = exp2f(m_run[j] - mn);  // == 1.0 when deferred
      m_run[j] = mn;
      int prow = w * 16 + lg * 4 + j;
#pragma unroll
      for (int n = 0; n < 4; ++n) {
        float pp = exp2f(sacc[n][j] - mn);
        int col = n * 16 + lr;
        sPb[prow * 64 + (((col >> 3) ^ (prow & 7)) << 3) + (col & 7)] = f2bu(pp);
      }
    }
    if (__any(grow_any)) {
#pragma unroll
      for (int n = 0; n < 8; ++n)
#pragma unroll
        for (int j = 0; j < 4; ++j) oacc[n][j] *= corr_[j];
#pragma unroll
      for (int j = 0; j < 4; ++j) oacc_l[j] *= corr_[j];
    }
    // PV (P rows wave-private: no barrier). Extra ones-MFMA accumulates row sums.
    __builtin_amdgcn_s_setprio(1);
#pragma unroll
    for (int kk = 0; kk < 2; ++kk) {
      short8 ap, bv[8];
      {
        int row = w * 16 + lr;
        ap = pP[row * 8 + ((kk * 4 + lg) ^ (row & 7))];
      }
#pragma unroll
      for (int n = 0; n < 8; ++n) {
        int row = n * 16 + lr;
        bv[n] = pV[row * 8 + ((kk * 4 + lg) ^ (row & 7))];
      }
#pragma unroll
      for (int n = 0; n < 8; ++n)
        oacc[n] = __builtin_amdgcn_mfma_f32_16x16x32_bf16(ap, bv[n], oacc[n], 0, 0, 0);
      oacc_l = __builtin_amdgcn_mfma_f32_16x16x32_bf16(ap, ones8, oacc_l, 0, 0, 0);
    }
    __builtin_amdgcn_s_setprio(0);
  }
  const size_t zbase = (size_t)z * 40960 + (size_t)h * 2560 + orow;
#pragma unroll
  for (int j = 0; j < 4; ++j) {
    int row = w * 16 + lg * 4 + j;
#pragma unroll
    for (int n = 0; n < 8; ++n)
      Op[(zbase + row) * 128 + n * 16 + lr] = f2bu(oacc[n][j]);
    if (lr == 0) {
      ml[(zbase + row) * 2] = m_run[j];
      ml[(zbase + row) * 2 + 1] = oacc_l[j];
    }
  }
}

// merge 4 KV-chunk partials (log2-domain LSE combine) -> ao[r][h*128+d] bf16
__global__ __launch_bounds__(256) void attn_merge(
    const unsigned short* __restrict__ Op, const float* __restrict__ ml,
    unsigned short* __restrict__ ao) {
  int gid = blockIdx.x * 256 + threadIdx.x;  // 40960 rows * 32 threads
  int rid = gid >> 5, d0 = (gid & 31) * 4;
  int h = rid / 2560;
  int r = rid - h * 2560;
  float M = -1e30f;
#pragma unroll
  for (int z = 0; z < 4; ++z) M = fmaxf(M, ml[((size_t)z * 40960 + rid) * 2]);
  float L = 0.f, o0 = 0.f, o1 = 0.f, o2 = 0.f, o3 = 0.f;
#pragma unroll
  for (int z = 0; z < 4; ++z) {
    size_t sidx = (size_t)z * 40960 + rid;
    float mz = ml[sidx * 2], lz = ml[sidx * 2 + 1];
    float wgt = exp2f(mz - M);
    L += wgt * lz;
    ushort4 v = *reinterpret_cast<const ushort4*>(Op + sidx * 128 + d0);
    o0 += wgt * b2f(v.x); o1 += wgt * b2f(v.y);
    o2 += wgt * b2f(v.z); o3 += wgt * b2f(v.w);
  }
  float inv = 1.f / L;
  ushort4 ov;
  ov.x = f2bu(o0 * inv); ov.y = f2bu(o1 * inv);
  ov.z = f2bu(o2 * inv); ov.w = f2bu(o3 * inv);
  *reinterpret_cast<ushort4*>(ao + (size_t)r * 2048 + h * 128 + d0) = ov;
}

// ---------------- residuals (sum 2 split-K partials) ----------------
__global__ __launch_bounds__(256) void residual1(
    const float4* __restrict__ X, const float4* __restrict__ P0,
    const float4* __restrict__ P1, const float* __restrict__ e,
    float4* __restrict__ out, int total4) {
  int stride = gridDim.x * 256;
  for (int i = blockIdx.x * 256 + threadIdx.x; i < total4; i += stride) {
    int c = (i * 4) & 2047;
    float4 g = *reinterpret_cast<const float4*>(e + 4096 + c);
    float4 x = X[i], p0 = P0[i], p1 = P1[i], o;
    o.x = x.x + g.x * (p0.x + p1.x); o.y = x.y + g.y * (p0.y + p1.y);
    o.z = x.z + g.z * (p0.z + p1.z); o.w = x.w + g.w * (p0.w + p1.w);
    out[i] = o;
  }
}

__global__ __launch_bounds__(256) void residual2(
    const float4* __restrict__ P0, const float4* __restrict__ P1,
    const float* __restrict__ b2, const float* __restrict__ e,
    float4* __restrict__ out, int total4) {
  int stride = gridDim.x * 256;
  for (int i = blockIdx.x * 256 + threadIdx.x; i < total4; i += stride) {
    int c = (i * 4) & 2047;
    float4 g = *reinterpret_cast<const float4*>(e + 10240 + c);
    float4 bb = *reinterpret_cast<const float4*>(b2 + c);
    float4 p0 = P0[i], p1 = P1[i], o = out[i];
    o.x += g.x * (p0.x + p1.x + bb.x); o.y += g.y * (p0.y + p1.y + bb.y);
    o.z += g.z * (p0.z + p1.z + bb.z); o.w += g.w * (p0.w + p1.w + bb.w);
    out[i] = o;
  }
}

extern "C" void kernel_launch(void* const* d_in, const int* in_sizes, int n_in,
                              void* d_out, int out_size, void* d_ws, size_t ws_size,
                              hipStream_t stream) {
  (void)in_sizes; (void)n_in; (void)out_size; (void)ws_size;
  const float* txt = (const float*)d_in[0];
  const float* img = (const float*)d_in[1];
  const float* vec = (const float*)d_in[2];
  const float* rope = (const float*)d_in[3];
  const float* sol_t = (const float*)d_in[4];
  const float* sol_s = (const float*)d_in[5];
  const float* ada_img_w = (const float*)d_in[6];
  const float* ada_img_b = (const float*)d_in[7];
  const float* ada_img_nw = (const float*)d_in[8];
  const float* ada_txt_w = (const float*)d_in[9];
  const float* ada_txt_b = (const float*)d_in[10];
  const float* ada_txt_nw = (const float*)d_in[11];
  const float* txt_qkv_w = (const float*)d_in[12];
  const float* img_qkv_w = (const float*)d_in[13];
  const float* txt_out_w = (const float*)d_in[14];
  const float* img_out_w = (const float*)d_in[15];
  const float* mod_w = (const float*)d_in[16];
  const float* mod_b = (const float*)d_in[17];
  const float* img_n2_w = (const float*)d_in[18];
  const float* txt_n2_w = (const float*)d_in[19];
  const float* img_fc1_w = (const float*)d_in[20];
  const float* img_fc1_b = (const float*)d_in[21];
  const float* img_fc2_w = (const float*)d_in[22];
  const float* img_fc2_b = (const float*)d_in[23];
  const float* txt_fc1_w = (const float*)d_in[24];
  const float* txt_fc1_b = (const float*)d_in[25];
  const float* txt_fc2_w = (const float*)d_in[26];
  const float* txt_fc2_b = (const float*)d_in[27];
  float* out = (float*)d_out;
  float* out_img = out + (size_t)512 * 2048;
  char* ws = (char*)d_ws;

  const size_t MB = 1 << 20;
  float* silu_vec = (float*)(ws + 0);
  float* scales = (float*)(ws + 8192);
  float* modb = (float*)(ws + 16384);
  float* e_img = (float*)(ws + 147456);
  float* e_txt = (float*)(ws + 196608);
  unsigned short* wt0 = (unsigned short*)(ws + 1 * MB);    // 32MB txt weights
  unsigned short* wt1 = (unsigned short*)(ws + 33 * MB);   // 32MB img weights
  unsigned short* Opart = (unsigned short*)(ws + 1 * MB);  // 40MB (overlays weights, dead then)
  float* mlbuf = (float*)(ws + 42 * MB);                   // 1.25MB
  unsigned short* actA = (unsigned short*)(ws + 65 * MB);  // [2560][2048] bf16, 10MB
  char* attn_base = ws + 75 * MB;                          // 50MB region
  unsigned short* q_txt = (unsigned short*)(attn_base);
  unsigned short* q_img = (unsigned short*)(attn_base + 2 * MB);
  unsigned short* k_cat = (unsigned short*)(attn_base + 10 * MB);
  unsigned short* v_cat = (unsigned short*)(attn_base + 20 * MB);
  unsigned short* vT = (unsigned short*)(attn_base + 30 * MB);
  unsigned short* ao = (unsigned short*)(attn_base + 40 * MB);
  unsigned short* actB = (unsigned short*)attn_base;  // [2560][8192] bf16 (MLP phase)
  float* Cbuf = (float*)(ws + 125 * MB);  // 2 partials x [2560][2048] f32 = 40MB
  const size_t PSTR = (size_t)2560 * 2048;

  prep_small<<<1, 256, 0, stream>>>(vec, sol_t, silu_vec, scales);
  mod_kernel<<<128, 256, 0, stream>>>(sol_s, mod_w, mod_b, modb);
  ada_gemv<<<dim3(192, 2), 256, 0, stream>>>(silu_vec, ada_img_w, ada_img_b,
                                             ada_txt_w, ada_txt_b, e_img, e_txt);
  rmsmod_kernel<<<512, 256, 0, stream>>>(txt, ada_txt_nw, e_txt, 0, 2048, actA);
  rmsmod_kernel<<<2048, 256, 0, stream>>>(img, ada_img_nw, e_img, 0, 2048,
                                          actA + (size_t)512 * 2048);
  transpose_w<<<dim3(192, 32), 256, 0, stream>>>(txt_qkv_w, wt0, 2048, 6144);
  transpose_w<<<dim3(192, 32), 256, 0, stream>>>(img_qkv_w, wt1, 2048, 6144);
  {
    GemmP p = {actA, wt0, wt1, nullptr, nullptr, nullptr, nullptr,
               rope, modb, q_txt, q_img, k_cat, v_cat, scales, 4, 6144, 2048, 1};
    gemm2<2><<<dim3(48, 20, 1), 256, 0, stream>>>(p);
  }
  transpose_v<<<dim3(80, 4, 16), dim3(32, 8), 0, stream>>>(v_cat, vT);
  attn_kernel<<<dim3(40, 16, 4), 256, 0, stream>>>(q_txt, q_img, k_cat, vT, Opart, mlbuf);
  attn_merge<<<5120, 256, 0, stream>>>(Opart, mlbuf, ao);
  transpose_w<<<dim3(64, 32), 256, 0, stream>>>(txt_out_w, wt0, 2048, 2048);
  transpose_w<<<dim3(64, 32), 256, 0, stream>>>(img_out_w, wt1, 2048, 2048);
  {
    GemmP p = {ao, wt0, wt1, Cbuf, nullptr, nullptr, nullptr,
               nullptr, nullptr, nullptr, nullptr, nullptr, nullptr, nullptr, 4, 2048, 2048, 2};
    gemm2<0><<<dim3(16, 20, 2), 256, 0, stream>>>(p);
  }
  residual1<<<512, 256, 0, stream>>>((const float4*)txt, (const float4*)Cbuf,
                                     (const float4*)(Cbuf + PSTR), e_txt,
                                     (float4*)out, 512 * 2048 / 4);
  residual1<<<1024, 256, 0, stream>>>((const float4*)img,
                                      (const float4*)(Cbuf + (size_t)512 * 2048),
                                      (const float4*)(Cbuf + PSTR + (size_t)512 * 2048), e_img,
                                      (float4*)out_img, 2048 * 2048 / 4);
  rmsmod_kernel<<<512, 256, 0, stream>>>(out, txt_n2_w, e_txt, 6144, 8192, actA);
  rmsmod_kernel<<<2048, 256, 0, stream>>>(out_img, img_n2_w, e_img, 6144, 8192,
                                          actA + (size_t)512 * 2048);
  transpose_w<<<dim3(256, 32), 256, 0, stream>>>(txt_fc1_w, wt0, 2048, 8192);
  transpose_w<<<dim3(256, 32), 256, 0, stream>>>(img_fc1_w, wt1, 2048, 8192);
  {
    GemmP p = {actA, wt0, wt1, nullptr, actB, txt_fc1_b, img_fc1_b,
               nullptr, nullptr, nullptr, nullptr, nullptr, nullptr, nullptr, 4, 8192, 2048, 1};
    gemm2<1><<<dim3(64, 20, 1), 256, 0, stream>>>(p);
  }
  transpose_w<<<dim3(64, 128), 256, 0, stream>>>(txt_fc2_w, wt0, 8192, 2048);
  transpose_w<<<dim3(64, 128), 256, 0, stream>>>(img_fc2_w, wt1, 8192, 2048);
  {
    GemmP p = {actB, wt0, wt1, Cbuf, nullptr, nullptr, nullptr,
               nullptr, nullptr, nullptr, nullptr, nullptr, nullptr, nullptr, 4, 2048, 8192, 2};
    gemm2<0><<<dim3(16, 20, 2), 256, 0, stream>>>(p);
  }
  residual2<<<512, 256, 0, stream>>>((const float4*)Cbuf, (const float4*)(Cbuf + PSTR),
                                     txt_fc2_b, e_txt, (float4*)out, 512 * 2048 / 4);
  residual2<<<1024, 256, 0, stream>>>((const float4*)(Cbuf + (size_t)512 * 2048),
                                      (const float4*)(Cbuf + PSTR + (size_t)512 * 2048),
                                      img_fc2_b, e_img, (float4*)out_img, 2048 * 2048 / 4);
}